// Round 5
// baseline (1255.067 us; speedup 1.0000x reference)
//
#include <hip/hip_runtime.h>

#define H       64
#define NSLOT   4
#define NSTEP   23          // SEQ_LEN - 1
#define NB      65536
#define NV      66          // VOCAB_SIZE + 2
#define SEQL    24
#define LPE     8           // lanes per element
#define TPB     512         // 8 waves
#define EPB     64          // G=1: one element per 8-lane group (R5: VGPR diet -> 2 blocks/CU)
#define ACTSTR  68          // act row stride: conflict-free b128 broadcast reads
#define MROW    68          // sM row stride
#define JL      48          // M rows j<JL from LDS; j>=JL from global (R0-proven pipe balance)
#define MSSTR   (JL * MROW + 4)   // 48*68+4=3268, 3268%32==4 (bank-offset invariant)

// R0/R3/R4 occupancy triangle: same 80896B LDS fit 2 blocks at VGPR=64 (R3, 42.7%)
// but only 1 block at VGPR=128 (R4, 21.5%) -> the 4-waves/SIMD boundary is
// vgpr <~ 112-127, NOT 128. G=1 cuts state (pmem 32 + contrib 8 + work ~60)
// to ~100 VGPR to get under it. LDS here: 52288+17408+1088+1152 = 71936B;
// 2 blocks = ~144KB <= 160KB.

// ---- workspace layout (float offsets) ----
#define OFF_EW1   0                  // embW1b  [NV][H] = embed@W1[:64] + b1
#define OFF_EWR1  (NV * H)           // embWr1b [NV][H] = embed@Wr1[:64] + br1
#define OFF_M     (2 * NV * H)       // M [4][64][64] = Ww @ W1slot_s
#define OFF_PB    (OFF_M + NSLOT * H * H)   // pb [4][64] = bw @ W1slot_s
#define OFF_HL    (OFF_PB + NSLOT * H)      // hlast [NB][4][64]  (64 MB)

__global__ __launch_bounds__(256) void k_setup_tables(
    const float* __restrict__ embed, const float* __restrict__ W1, const float* __restrict__ b1,
    const float* __restrict__ Wr1, const float* __restrict__ br1, float* __restrict__ ws)
{
    int idx = blockIdx.x * 256 + threadIdx.x;
    if (idx >= NV * H) return;
    int t = idx >> 6, k = idx & 63;
    float a1 = b1[k], a2 = br1[k];
    for (int j = 0; j < H; ++j) {
        float e = embed[t * H + j];
        a1 = fmaf(e, W1[j * H + k], a1);
        a2 = fmaf(e, Wr1[j * H + k], a2);
    }
    ws[OFF_EW1 + idx]  = a1;
    ws[OFF_EWR1 + idx] = a2;
}

__global__ __launch_bounds__(256) void k_setup_fuse(
    const float* __restrict__ W1, const float* __restrict__ Ww, const float* __restrict__ bw,
    float* __restrict__ ws)
{
    int idx = blockIdx.x * 256 + threadIdx.x;
    if (idx < NSLOT * H * H) {
        int s = idx >> 12, j = (idx >> 6) & 63, k = idx & 63;
        const float* w1s = W1 + (size_t)(H + s * H) * H;   // [p][k]
        float acc = 0.f;
        for (int p = 0; p < H; ++p)
            acc = fmaf(Ww[j * H + p], w1s[p * H + k], acc);
        ws[OFF_M + idx] = acc;
    } else if (idx < NSLOT * H * H + NSLOT * H) {
        int r = idx - NSLOT * H * H;
        int s = r >> 6, k = r & 63;
        const float* w1s = W1 + (size_t)(H + s * H) * H;
        float acc = 0.f;
        for (int p = 0; p < H; ++p)
            acc = fmaf(bw[p], w1s[p * H + k], acc);
        ws[OFF_PB + r] = acc;
    }
}

#define FMA8V(w0, w1, a, ACC) do {                                          \
    ACC[0]=fmaf((a),w0.x,ACC[0]); ACC[1]=fmaf((a),w0.y,ACC[1]);            \
    ACC[2]=fmaf((a),w0.z,ACC[2]); ACC[3]=fmaf((a),w0.w,ACC[3]);            \
    ACC[4]=fmaf((a),w1.x,ACC[4]); ACC[5]=fmaf((a),w1.y,ACC[5]);            \
    ACC[6]=fmaf((a),w1.z,ACC[6]); ACC[7]=fmaf((a),w1.w,ACC[7]);            \
} while (0)

#define LOAD8(ptr, A) do {                                                  \
    const float4* _b = (const float4*)(ptr);                                \
    float4 _b0 = _b[0], _b1 = _b[1];                                        \
    A[0]=_b0.x; A[1]=_b0.y; A[2]=_b0.z; A[3]=_b0.w;                        \
    A[4]=_b1.x; A[5]=_b1.y; A[6]=_b1.z; A[7]=_b1.w;                        \
} while (0)

#define STORE8(rowptr, A) do {                                              \
    float4* _d = (float4*)(rowptr);                                         \
    _d[0] = make_float4(A[0], A[1], A[2], A[3]);                            \
    _d[1] = make_float4(A[4], A[5], A[6], A[7]);                            \
} while (0)

__global__ __launch_bounds__(TPB, 2) void k_main(
    const float* __restrict__ W2, const float* __restrict__ b2,
    const float* __restrict__ Ww, const float* __restrict__ bw,
    const float* __restrict__ We, const float* __restrict__ be,
    const float* __restrict__ Wr1, const float* __restrict__ Wr2, const float* __restrict__ br2,
    const int* __restrict__ qtok, const int* __restrict__ seqs,
    const float* __restrict__ ws, float* hl, float* __restrict__ out)
{
    __shared__ float sM[NSLOT * MSSTR];    // M rows j<JL  ~51 KB
    __shared__ float sAct[EPB * ACTSTR];   // [elem][j] rows ~17 KB
    __shared__ float sPb[NSLOT * 68];      // pb_s rows
    __shared__ float sWeS[8 * 36];         // per-chunk We slices [m][i*4+s]

    const int tid  = threadIdx.x;
    const int m    = tid & (LPE - 1);
    const int g    = tid >> 3;             // element group 0..63 (8 lanes, same wave)
    const int eA   = g;
    const int gidA = blockIdx.x * EPB + eA;
    const int k0   = m * 8;

    // ---- stage LDS ----
    if (tid < 256) {                        // sM: rows j<JL of each slot
        int s = tid >> 6, j = tid & 63;
        if (j < JL) {
            const float4* src = (const float4*)(ws + OFF_M + (size_t)(s * H + j) * H);
            float4* dst = (float4*)(sM + s * MSSTR + j * MROW);
#pragma unroll
            for (int k = 0; k < 16; ++k) dst[k] = src[k];
        }
    }
    if (tid >= 256 && tid < 512) {
        int r = tid - 256;                  // sPb: 4 x 64
        int s = r >> 6, k = r & 63;
        sPb[s * 68 + k] = ws[OFF_PB + s * H + k];
    }
    if (tid < 256) {
        int mm = tid >> 5, rem = tid & 31;  // sWeS[m][i*4+s] = We[(m*8+i)*4+s]
        sWeS[mm * 36 + rem] = We[tid];
    }
    __syncthreads();

    const float* embW1b  = ws + OFF_EW1;
    const float* embWr1b = ws + OFF_EWR1;
    const float* Mg      = ws + OFF_M;      // global M (rows j>=JL read from here)
    float* hlA = hl + (size_t)gidA * (NSLOT * H) + k0;

    // register state per element: pmem 4x8 + contrib 8 + written-mask
    float pA0[8], pA1[8], pA2[8], pA3[8], cA[8];
#pragma unroll
    for (int i = 0; i < 8; ++i) {
        pA0[i]=0.f; pA1[i]=0.f; pA2[i]=0.f; pA3[i]=0.f; cA[i]=0.f;
    }
    int maskA = 0;

    float b2r[8];
    LOAD8(b2 + k0, b2r);
    const float4 be4 = *(const float4*)be;

    int tokA = seqs[gidA * SEQL];

    float accA[8];
    float* rowA = sAct + eA * ACTSTR;

#pragma unroll 1
    for (int t = 0; t < NSTEP; ++t) {
        int tokAn = seqs[gidA * SEQL + t + 1];

        // h1 = relu(embW1b[tok] + contrib) -> act row
        {
            float hA[8];
            LOAD8(embW1b + tokA * H + k0, hA);
#pragma unroll
            for (int i = 0; i < 8; ++i)
                hA[i] = fmaxf(hA[i] + cA[i], 0.f);
            STORE8(rowA + k0, hA);
        }

        // h2 = relu(h1 @ W2 + b2)   (W2 via VMEM; act b128 LDS broadcast)
#pragma unroll
        for (int i = 0; i < 8; ++i) accA[i] = b2r[i];
#pragma unroll 4
        for (int jq = 0; jq < 16; ++jq) {
            float4 a4 = *(const float4*)(rowA + jq * 4);
            float aAv[4] = {a4.x, a4.y, a4.z, a4.w};
#pragma unroll
            for (int jj = 0; jj < 4; ++jj) {
                const float4* w = (const float4*)(W2 + (jq * 4 + jj) * H + k0);
                float4 w0 = w[0], w1 = w[1];
                FMA8V(w0, w1, aAv[jj], accA);
            }
        }
        float h2A[8];
#pragma unroll
        for (int i = 0; i < 8; ++i)
            h2A[i] = fmaxf(accA[i], 0.f);
        STORE8(rowA + k0, h2A);

        // evict logits in-register, then 8-lane butterfly sum
        float lA0 = 0.f, lA1 = 0.f, lA2 = 0.f, lA3 = 0.f;
        {
            const float* wsl = sWeS + m * 36;
#pragma unroll
            for (int i = 0; i < 8; ++i) {
                float4 we4 = *(const float4*)(wsl + i * 4);
                lA0 = fmaf(h2A[i], we4.x, lA0); lA1 = fmaf(h2A[i], we4.y, lA1);
                lA2 = fmaf(h2A[i], we4.z, lA2); lA3 = fmaf(h2A[i], we4.w, lA3);
            }
        }
#pragma unroll
        for (int d = 1; d <= 4; d <<= 1) {
            lA0 += __shfl_xor(lA0, d); lA1 += __shfl_xor(lA1, d);
            lA2 += __shfl_xor(lA2, d); lA3 += __shfl_xor(lA3, d);
        }
        lA0 += be4.x; lA1 += be4.y; lA2 += be4.z; lA3 += be4.w;

        int eSA = 0; float bstA = lA0;               // first-max wins = jnp.argmax
        if (lA1 > bstA) { bstA = lA1; eSA = 1; }
        if (lA2 > bstA) { bstA = lA2; eSA = 2; }
        if (lA3 > bstA) { bstA = lA3; eSA = 3; }

        bool a0 = (eSA == 0), a1 = (eSA == 1), a2 = (eSA == 2), a3 = (eSA == 3);

        // hlast[e] <- h2  (global, fire-and-forget; read back only at tail)
        STORE8(hlA + eSA * H, h2A);
        maskA |= (1 << eSA);

        // pv = h2 @ M_e + pb_e   — rows j<JL from LDS, rows j>=JL from global.
        LOAD8(sPb + eSA * 68 + k0, accA);
        const float* lMA = sM + eSA * MSSTR + k0;
#pragma unroll 4
        for (int jq = 0; jq < JL / 4; ++jq) {
            float4 a4 = *(const float4*)(rowA + jq * 4);
            float dAv[4] = {a4.x, a4.y, a4.z, a4.w};
#pragma unroll
            for (int jj = 0; jj < 4; ++jj) {
                int j = jq * 4 + jj;
                const float4* wa = (const float4*)(lMA + j * MROW);
                float4 wa0 = wa[0], wa1 = wa[1];
                FMA8V(wa0, wa1, dAv[jj], accA);
            }
        }
        {
            const float* gMA = Mg + (size_t)(eSA * H + JL) * H + k0;  // rows JL..63
#pragma unroll 2
            for (int jq = JL / 4; jq < 16; ++jq) {
                float4 a4 = *(const float4*)(rowA + jq * 4);
                float dAv[4] = {a4.x, a4.y, a4.z, a4.w};
#pragma unroll
                for (int jj = 0; jj < 4; ++jj) {
                    int jr = (jq * 4 + jj) - JL;   // row offset within global part
                    const float4* wa = (const float4*)(gMA + jr * H);
                    float4 wa0 = wa[0], wa1 = wa[1];
                    FMA8V(wa0, wa1, dAv[jj], accA);
                }
            }
        }

        // contrib += pv - pmem[e] ; pmem[e] = pv
#pragma unroll
        for (int i = 0; i < 8; ++i) {
            float pvA = accA[i];
            float oldA = a0 ? pA0[i] : a1 ? pA1[i] : a2 ? pA2[i] : pA3[i];
            cA[i] += pvA - oldA;
            pA0[i] = a0 ? pvA : pA0[i];  pA1[i] = a1 ? pvA : pA1[i];
            pA2[i] = a2 ? pvA : pA2[i];  pA3[i] = a3 ? pvA : pA3[i];
        }

        tokA = tokAn;
    }

    // ---- tail: hsum = sum of surviving hlast slots (read back from global) ----
    __threadfence();   // drain hlast stores before read-back
    {
        float hsA[8] = {0,0,0,0,0,0,0,0};
#pragma unroll
        for (int s = 0; s < NSLOT; ++s) {
            float vA[8];
            LOAD8(hlA + s * H, vA);
            float fA = ((maskA >> s) & 1) ? 1.f : 0.f;
#pragma unroll
            for (int i = 0; i < 8; ++i)
                hsA[i] = fmaf(fA, vA[i], hsA[i]);
        }
        STORE8(rowA + k0, hsA);
    }

    // msum = (hsum @ Ww + cnt*bw) / 4
    {
        float bwr[8];
        LOAD8(bw + k0, bwr);
        float cntA = (float)__popc(maskA);
#pragma unroll
        for (int i = 0; i < 8; ++i) accA[i] = cntA * bwr[i];
    }
#pragma unroll 4
    for (int jq = 0; jq < 16; ++jq) {
        float4 a4 = *(const float4*)(rowA + jq * 4);
        float aAv[4] = {a4.x, a4.y, a4.z, a4.w};
#pragma unroll
        for (int jj = 0; jj < 4; ++jj) {
            const float4* w = (const float4*)(Ww + (jq * 4 + jj) * H + k0);
            float4 w0 = w[0], w1 = w[1];
            FMA8V(w0, w1, aAv[jj], accA);
        }
    }
    {
        float msA[8];
#pragma unroll
        for (int i = 0; i < 8; ++i)
            msA[i] = accA[i] * 0.25f;
        STORE8(rowA + k0, msA);
    }

    // r2 = relu(embWr1b[q] + msum @ Wr1[64:128])
    int qA = qtok[gidA];
    LOAD8(embWr1b + qA * H + k0, accA);
#pragma unroll 4
    for (int jq = 0; jq < 16; ++jq) {
        float4 a4 = *(const float4*)(rowA + jq * 4);
        float aAv[4] = {a4.x, a4.y, a4.z, a4.w};
#pragma unroll
        for (int jj = 0; jj < 4; ++jj) {
            const float4* w = (const float4*)(Wr1 + (H + jq * 4 + jj) * H + k0);
            float4 w0 = w[0], w1 = w[1];
            FMA8V(w0, w1, aAv[jj], accA);
        }
    }
    {
        float rA[8];
#pragma unroll
        for (int i = 0; i < 8; ++i)
            rA[i] = fmaxf(accA[i], 0.f);
        STORE8(rowA + k0, rA);
    }

    // logits = r2 @ Wr2 + br2
    LOAD8(br2 + k0, accA);
#pragma unroll 4
    for (int jq = 0; jq < 16; ++jq) {
        float4 a4 = *(const float4*)(rowA + jq * 4);
        float aAv[4] = {a4.x, a4.y, a4.z, a4.w};
#pragma unroll
        for (int jj = 0; jj < 4; ++jj) {
            const float4* w = (const float4*)(Wr2 + (jq * 4 + jj) * H + k0);
            float4 w0 = w[0], w1 = w[1];
            FMA8V(w0, w1, aAv[jj], accA);
        }
    }

    float4* oA = (float4*)(out + (size_t)gidA * H + k0);
    oA[0] = make_float4(accA[0], accA[1], accA[2], accA[3]);
    oA[1] = make_float4(accA[4], accA[5], accA[6], accA[7]);
}

extern "C" void kernel_launch(void* const* d_in, const int* in_sizes, int n_in,
                              void* d_out, int out_size, void* d_ws, size_t ws_size,
                              hipStream_t stream)
{
    const int*   seqs  = (const int*)d_in[0];
    const int*   qtok  = (const int*)d_in[1];
    const float* embed = (const float*)d_in[2];
    const float* W1    = (const float*)d_in[3];
    const float* b1    = (const float*)d_in[4];
    const float* W2    = (const float*)d_in[5];
    const float* b2    = (const float*)d_in[6];
    const float* Ww    = (const float*)d_in[7];
    const float* bw    = (const float*)d_in[8];
    const float* We    = (const float*)d_in[9];
    const float* be    = (const float*)d_in[10];
    const float* Wr1   = (const float*)d_in[11];
    const float* br1   = (const float*)d_in[12];
    const float* Wr2   = (const float*)d_in[13];
    const float* br2   = (const float*)d_in[14];
    float* out = (float*)d_out;
    float* ws  = (float*)d_ws;

    hipLaunchKernelGGL(k_setup_tables, dim3((NV * H + 255) / 256), dim3(256), 0, stream,
                       embed, W1, b1, Wr1, br1, ws);
    hipLaunchKernelGGL(k_setup_fuse, dim3((NSLOT * H * H + NSLOT * H + 255) / 256), dim3(256),
                       0, stream, W1, Ww, bw, ws);
    hipLaunchKernelGGL(k_main, dim3(NB / EPB), dim3(TPB), 0, stream,
                       W2, b2, Ww, bw, We, be, Wr1, Wr2, br2, qtok, seqs,
                       ws, ws + OFF_HL, out);
}

// Round 6
// 1113.369 us; speedup vs baseline: 1.1273x; 1.1273x over previous
//
#include <hip/hip_runtime.h>

#define H       64
#define NSLOT   4
#define NSTEP   23          // SEQ_LEN - 1
#define NB      65536
#define NV      66          // VOCAB_SIZE + 2
#define SEQL    24
#define LPE     8           // lanes per element
#define TPB     512         // 8 waves
#define EPB     128         // elements per block (G=2 per lane)
#define ACTSTR  68          // act row stride: conflict-free b128 broadcast reads
#define MROW    68          // sM row stride
#define JL      48          // M rows j<JL from LDS; j>=JL from global (R0-proven balance)
#define MSSTR   (JL * MROW + 4)   // 48*68+4=3268 ; 3268%32==4 (bank-offset invariant)

// Occupancy post-mortem (R0/R3/R4/R5): 8 waves/CU for VGPR in [88,128] at any LDS
// 72-90KB; 16 waves only at VGPR=64 (spill-city). Lever abandoned. This version
// instead FUSES each element's PV (DS-pipe) with the OTHER element's W2 (VMEM-pipe)
// into one loop body so both pipes are fed concurrently by one wave (they were
// phase-serialized in separate basic blocks before). Last-step PV is dead -> skipped.

// ---- workspace layout (float offsets) ----
#define OFF_EW1   0                  // embW1b  [NV][H] = embed@W1[:64] + b1
#define OFF_EWR1  (NV * H)           // embWr1b [NV][H] = embed@Wr1[:64] + br1
#define OFF_M     (2 * NV * H)       // M [4][64][64] = Ww @ W1slot_s
#define OFF_PB    (OFF_M + NSLOT * H * H)   // pb [4][64] = bw @ W1slot_s
#define OFF_HL    (OFF_PB + NSLOT * H)      // hlast [NB][4][64]  (64 MB)

__global__ __launch_bounds__(256) void k_setup_tables(
    const float* __restrict__ embed, const float* __restrict__ W1, const float* __restrict__ b1,
    const float* __restrict__ Wr1, const float* __restrict__ br1, float* __restrict__ ws)
{
    int idx = blockIdx.x * 256 + threadIdx.x;
    if (idx >= NV * H) return;
    int t = idx >> 6, k = idx & 63;
    float a1 = b1[k], a2 = br1[k];
    for (int j = 0; j < H; ++j) {
        float e = embed[t * H + j];
        a1 = fmaf(e, W1[j * H + k], a1);
        a2 = fmaf(e, Wr1[j * H + k], a2);
    }
    ws[OFF_EW1 + idx]  = a1;
    ws[OFF_EWR1 + idx] = a2;
}

__global__ __launch_bounds__(256) void k_setup_fuse(
    const float* __restrict__ W1, const float* __restrict__ Ww, const float* __restrict__ bw,
    float* __restrict__ ws)
{
    int idx = blockIdx.x * 256 + threadIdx.x;
    if (idx < NSLOT * H * H) {
        int s = idx >> 12, j = (idx >> 6) & 63, k = idx & 63;
        const float* w1s = W1 + (size_t)(H + s * H) * H;   // [p][k]
        float acc = 0.f;
        for (int p = 0; p < H; ++p)
            acc = fmaf(Ww[j * H + p], w1s[p * H + k], acc);
        ws[OFF_M + idx] = acc;
    } else if (idx < NSLOT * H * H + NSLOT * H) {
        int r = idx - NSLOT * H * H;
        int s = r >> 6, k = r & 63;
        const float* w1s = W1 + (size_t)(H + s * H) * H;
        float acc = 0.f;
        for (int p = 0; p < H; ++p)
            acc = fmaf(bw[p], w1s[p * H + k], acc);
        ws[OFF_PB + r] = acc;
    }
}

#define FMA8V(w0, w1, a, ACC) do {                                          \
    ACC[0]=fmaf((a),w0.x,ACC[0]); ACC[1]=fmaf((a),w0.y,ACC[1]);            \
    ACC[2]=fmaf((a),w0.z,ACC[2]); ACC[3]=fmaf((a),w0.w,ACC[3]);            \
    ACC[4]=fmaf((a),w1.x,ACC[4]); ACC[5]=fmaf((a),w1.y,ACC[5]);            \
    ACC[6]=fmaf((a),w1.z,ACC[6]); ACC[7]=fmaf((a),w1.w,ACC[7]);            \
} while (0)

#define LOAD8(ptr, A) do {                                                  \
    const float4* _b = (const float4*)(ptr);                                \
    float4 _b0 = _b[0], _b1 = _b[1];                                        \
    A[0]=_b0.x; A[1]=_b0.y; A[2]=_b0.z; A[3]=_b0.w;                        \
    A[4]=_b1.x; A[5]=_b1.y; A[6]=_b1.z; A[7]=_b1.w;                        \
} while (0)

#define STORE8(rowptr, A) do {                                              \
    float4* _d = (float4*)(rowptr);                                         \
    _d[0] = make_float4(A[0], A[1], A[2], A[3]);                            \
    _d[1] = make_float4(A[4], A[5], A[6], A[7]);                            \
} while (0)

// PV(X) over M (DS for j<JL, global for j>=JL) fused with W2(Y) (VMEM) — one
// basic block so the scheduler interleaves DS and VMEM issue.
__device__ __forceinline__ void merged_pv_w2(
    const float* rowPV, const float* rowW2,
    const float* lM, const float* gM, const float* W2k,
    float accPV[8], float accW2[8])
{
#pragma unroll 4
    for (int jq = 0; jq < JL / 4; ++jq) {
        float4 p4 = *(const float4*)(rowPV + jq * 4);
        float4 w4 = *(const float4*)(rowW2 + jq * 4);
        float pv_[4] = {p4.x, p4.y, p4.z, p4.w};
        float wv_[4] = {w4.x, w4.y, w4.z, w4.w};
#pragma unroll
        for (int jj = 0; jj < 4; ++jj) {
            int j = jq * 4 + jj;
            const float4* wm = (const float4*)(lM + j * MROW);
            float4 m0 = wm[0], m1 = wm[1];
            const float4* wp = (const float4*)(W2k + j * H);
            float4 w0 = wp[0], w1 = wp[1];
            FMA8V(m0, m1, pv_[jj], accPV);
            FMA8V(w0, w1, wv_[jj], accW2);
        }
    }
#pragma unroll 2
    for (int jq = JL / 4; jq < 16; ++jq) {
        float4 p4 = *(const float4*)(rowPV + jq * 4);
        float4 w4 = *(const float4*)(rowW2 + jq * 4);
        float pv_[4] = {p4.x, p4.y, p4.z, p4.w};
        float wv_[4] = {w4.x, w4.y, w4.z, w4.w};
#pragma unroll
        for (int jj = 0; jj < 4; ++jj) {
            int j = jq * 4 + jj;
            const float4* wm = (const float4*)(gM + (j - JL) * H);
            float4 m0 = wm[0], m1 = wm[1];
            const float4* wp = (const float4*)(W2k + j * H);
            float4 w0 = wp[0], w1 = wp[1];
            FMA8V(m0, m1, pv_[jj], accPV);
            FMA8V(w0, w1, wv_[jj], accW2);
        }
    }
}

__device__ __forceinline__ void w2_only(const float* rowW2, const float* W2k, float accW2[8])
{
#pragma unroll 4
    for (int jq = 0; jq < 16; ++jq) {
        float4 w4 = *(const float4*)(rowW2 + jq * 4);
        float wv_[4] = {w4.x, w4.y, w4.z, w4.w};
#pragma unroll
        for (int jj = 0; jj < 4; ++jj) {
            const float4* wp = (const float4*)(W2k + (jq * 4 + jj) * H);
            float4 w0 = wp[0], w1 = wp[1];
            FMA8V(w0, w1, wv_[jj], accW2);
        }
    }
}

__device__ __forceinline__ int evict_sel(const float h2[8], const float* wsl, float4 be4)
{
    float l0 = 0.f, l1 = 0.f, l2 = 0.f, l3 = 0.f;
#pragma unroll
    for (int i = 0; i < 8; ++i) {
        float4 we4 = *(const float4*)(wsl + i * 4);
        l0 = fmaf(h2[i], we4.x, l0); l1 = fmaf(h2[i], we4.y, l1);
        l2 = fmaf(h2[i], we4.z, l2); l3 = fmaf(h2[i], we4.w, l3);
    }
#pragma unroll
    for (int d = 1; d <= 4; d <<= 1) {
        l0 += __shfl_xor(l0, d); l1 += __shfl_xor(l1, d);
        l2 += __shfl_xor(l2, d); l3 += __shfl_xor(l3, d);
    }
    l0 += be4.x; l1 += be4.y; l2 += be4.z; l3 += be4.w;
    int e = 0; float b = l0;                       // first-max wins = jnp.argmax
    if (l1 > b) { b = l1; e = 1; }
    if (l2 > b) { b = l2; e = 2; }
    if (l3 > b) { b = l3; e = 3; }
    return e;
}

__device__ __forceinline__ void upd_contrib(int eS, const float pv[8], float c[8],
                                            float p0[8], float p1[8], float p2[8], float p3[8])
{
    bool f0 = (eS == 0), f1 = (eS == 1), f2 = (eS == 2), f3 = (eS == 3);
#pragma unroll
    for (int i = 0; i < 8; ++i) {
        float v = pv[i];
        float old = f0 ? p0[i] : f1 ? p1[i] : f2 ? p2[i] : p3[i];
        c[i] += v - old;
        p0[i] = f0 ? v : p0[i]; p1[i] = f1 ? v : p1[i];
        p2[i] = f2 ? v : p2[i]; p3[i] = f3 ? v : p3[i];
    }
}

__global__ __launch_bounds__(TPB, 1) void k_main(
    const float* __restrict__ W2, const float* __restrict__ b2,
    const float* __restrict__ Ww, const float* __restrict__ bw,
    const float* __restrict__ We, const float* __restrict__ be,
    const float* __restrict__ Wr1, const float* __restrict__ Wr2, const float* __restrict__ br2,
    const int* __restrict__ qtok, const int* __restrict__ seqs,
    const float* __restrict__ ws, float* hl, float* __restrict__ out)
{
    __shared__ float sM[NSLOT * MSSTR];    // M rows j<JL  ~52 KB
    __shared__ float sAct[EPB * ACTSTR];   // [elem][j] rows ~35 KB
    __shared__ float sPb[NSLOT * 68];      // pb_s rows
    __shared__ float sWeS[8 * 36];         // per-chunk We slices [m][i*4+s]

    const int tid  = threadIdx.x;
    const int m    = tid & (LPE - 1);
    const int g    = tid >> 3;
    const int eA   = g;
    const int eB   = g + 64;
    const int gidA = blockIdx.x * EPB + eA;
    const int gidB = blockIdx.x * EPB + eB;
    const int k0   = m * 8;

    // ---- stage LDS ----
    if (tid < 256) {
        int s = tid >> 6, j = tid & 63;
        if (j < JL) {
            const float4* src = (const float4*)(ws + OFF_M + (size_t)(s * H + j) * H);
            float4* dst = (float4*)(sM + s * MSSTR + j * MROW);
#pragma unroll
            for (int k = 0; k < 16; ++k) dst[k] = src[k];
        }
    }
    if (tid >= 256 && tid < 512) {
        int r = tid - 256;
        int s = r >> 6, k = r & 63;
        sPb[s * 68 + k] = ws[OFF_PB + s * H + k];
    }
    if (tid < 256) {
        int mm = tid >> 5, rem = tid & 31;
        sWeS[mm * 36 + rem] = We[tid];
    }
    __syncthreads();

    const float* embW1b  = ws + OFF_EW1;
    const float* embWr1b = ws + OFF_EWR1;
    const float* Mg      = ws + OFF_M;
    const float* W2k     = W2 + k0;
    float* hlA = hl + (size_t)gidA * (NSLOT * H) + k0;
    float* hlB = hl + (size_t)gidB * (NSLOT * H) + k0;

    float pA0[8], pA1[8], pA2[8], pA3[8], cA[8];
    float pB0[8], pB1[8], pB2[8], pB3[8], cB[8];
#pragma unroll
    for (int i = 0; i < 8; ++i) {
        pA0[i]=0.f; pA1[i]=0.f; pA2[i]=0.f; pA3[i]=0.f; cA[i]=0.f;
        pB0[i]=0.f; pB1[i]=0.f; pB2[i]=0.f; pB3[i]=0.f; cB[i]=0.f;
    }
    int maskA = 0, maskB = 0;

    float b2r[8];
    LOAD8(b2 + k0, b2r);
    const float4 be4 = *(const float4*)be;

    int tokA = seqs[gidA * SEQL];
    int tokB = seqs[gidB * SEQL];

    float* rowA = sAct + eA * ACTSTR;
    float* rowB = sAct + eB * ACTSTR;

    int eSA;

    // ---- prologue: A step 0 (plain W2, no PV partner) ----
    {
        float hA[8];
        LOAD8(embW1b + tokA * H + k0, hA);
#pragma unroll
        for (int i = 0; i < 8; ++i) hA[i] = fmaxf(hA[i] + cA[i], 0.f);
        STORE8(rowA + k0, hA);
        float accWA[8];
#pragma unroll
        for (int i = 0; i < 8; ++i) accWA[i] = b2r[i];
        w2_only(rowA, W2k, accWA);
        float h2A[8];
#pragma unroll
        for (int i = 0; i < 8; ++i) h2A[i] = fmaxf(accWA[i], 0.f);
        STORE8(rowA + k0, h2A);
        eSA = evict_sel(h2A, sWeS + m * 36, be4);
        STORE8(hlA + eSA * H, h2A);
        maskA |= 1 << eSA;
    }

    // ---- main loop: staggered half-steps ----
#pragma unroll 1
    for (int t = 0; t < NSTEP - 1; ++t) {
        // B step t  ∥  PV_A(t)
        {
            float hB[8];
            LOAD8(embW1b + tokB * H + k0, hB);
#pragma unroll
            for (int i = 0; i < 8; ++i) hB[i] = fmaxf(hB[i] + cB[i], 0.f);
            STORE8(rowB + k0, hB);
        }
        {
            float accPA[8];
            LOAD8(sPb + eSA * 68 + k0, accPA);
            float accWB[8];
#pragma unroll
            for (int i = 0; i < 8; ++i) accWB[i] = b2r[i];
            merged_pv_w2(rowA, rowB,
                         sM + eSA * MSSTR + k0,
                         Mg + (size_t)(eSA * H + JL) * H + k0,
                         W2k, accPA, accWB);
            float h2B[8];
#pragma unroll
            for (int i = 0; i < 8; ++i) h2B[i] = fmaxf(accWB[i], 0.f);
            STORE8(rowB + k0, h2B);
            int eSB = evict_sel(h2B, sWeS + m * 36, be4);
            STORE8(hlB + eSB * H, h2B);
            maskB |= 1 << eSB;
            upd_contrib(eSA, accPA, cA, pA0, pA1, pA2, pA3);

            // A step t+1  ∥  PV_B(t)
            {
                int tokA1 = seqs[gidA * SEQL + t + 1];
                float hA[8];
                LOAD8(embW1b + tokA1 * H + k0, hA);
#pragma unroll
                for (int i = 0; i < 8; ++i) hA[i] = fmaxf(hA[i] + cA[i], 0.f);
                STORE8(rowA + k0, hA);
            }
            float accPB[8];
            LOAD8(sPb + eSB * 68 + k0, accPB);
            float accWA[8];
#pragma unroll
            for (int i = 0; i < 8; ++i) accWA[i] = b2r[i];
            merged_pv_w2(rowB, rowA,
                         sM + eSB * MSSTR + k0,
                         Mg + (size_t)(eSB * H + JL) * H + k0,
                         W2k, accPB, accWA);
            float h2A[8];
#pragma unroll
            for (int i = 0; i < 8; ++i) h2A[i] = fmaxf(accWA[i], 0.f);
            STORE8(rowA + k0, h2A);
            eSA = evict_sel(h2A, sWeS + m * 36, be4);
            STORE8(hlA + eSA * H, h2A);
            maskA |= 1 << eSA;
            upd_contrib(eSB, accPB, cB, pB0, pB1, pB2, pB3);
        }
        tokB = seqs[gidB * SEQL + t + 1];
    }

    // ---- epilogue: B step 22 (plain W2; final-step PV is dead) ----
    {
        float hB[8];
        LOAD8(embW1b + tokB * H + k0, hB);
#pragma unroll
        for (int i = 0; i < 8; ++i) hB[i] = fmaxf(hB[i] + cB[i], 0.f);
        STORE8(rowB + k0, hB);
        float accWB[8];
#pragma unroll
        for (int i = 0; i < 8; ++i) accWB[i] = b2r[i];
        w2_only(rowB, W2k, accWB);
        float h2B[8];
#pragma unroll
        for (int i = 0; i < 8; ++i) h2B[i] = fmaxf(accWB[i], 0.f);
        STORE8(rowB + k0, h2B);
        int eSB = evict_sel(h2B, sWeS + m * 36, be4);
        STORE8(hlB + eSB * H, h2B);
        maskB |= 1 << eSB;
    }

    // ---- tail: hsum = sum of surviving hlast slots ----
    __threadfence();
    float accA[8], accB[8];
    {
        float hsA[8] = {0,0,0,0,0,0,0,0}, hsB[8] = {0,0,0,0,0,0,0,0};
#pragma unroll
        for (int s = 0; s < NSLOT; ++s) {
            float vA[8], vB[8];
            LOAD8(hlA + s * H, vA);
            LOAD8(hlB + s * H, vB);
            float fA = ((maskA >> s) & 1) ? 1.f : 0.f;
            float fB = ((maskB >> s) & 1) ? 1.f : 0.f;
#pragma unroll
            for (int i = 0; i < 8; ++i) {
                hsA[i] = fmaf(fA, vA[i], hsA[i]);
                hsB[i] = fmaf(fB, vB[i], hsB[i]);
            }
        }
        STORE8(rowA + k0, hsA);
        STORE8(rowB + k0, hsB);
    }

    // msum = (hsum @ Ww + cnt*bw) / 4
    {
        float bwr[8];
        LOAD8(bw + k0, bwr);
        float cntA = (float)__popc(maskA), cntB = (float)__popc(maskB);
#pragma unroll
        for (int i = 0; i < 8; ++i) { accA[i] = cntA * bwr[i]; accB[i] = cntB * bwr[i]; }
    }
#pragma unroll 4
    for (int jq = 0; jq < 16; ++jq) {
        float4 a4 = *(const float4*)(rowA + jq * 4);
        float4 b4 = *(const float4*)(rowB + jq * 4);
        float aAv[4] = {a4.x, a4.y, a4.z, a4.w};
        float aBv[4] = {b4.x, b4.y, b4.z, b4.w};
#pragma unroll
        for (int jj = 0; jj < 4; ++jj) {
            const float4* w = (const float4*)(Ww + (jq * 4 + jj) * H + k0);
            float4 w0 = w[0], w1 = w[1];
            FMA8V(w0, w1, aAv[jj], accA);
            FMA8V(w0, w1, aBv[jj], accB);
        }
    }
    {
        float msA[8], msB[8];
#pragma unroll
        for (int i = 0; i < 8; ++i) {
            msA[i] = accA[i] * 0.25f;
            msB[i] = accB[i] * 0.25f;
        }
        STORE8(rowA + k0, msA);
        STORE8(rowB + k0, msB);
    }

    // r2 = relu(embWr1b[q] + msum @ Wr1[64:128])
    int qA = qtok[gidA], qB = qtok[gidB];
    LOAD8(embWr1b + qA * H + k0, accA);
    LOAD8(embWr1b + qB * H + k0, accB);
#pragma unroll 4
    for (int jq = 0; jq < 16; ++jq) {
        float4 a4 = *(const float4*)(rowA + jq * 4);
        float4 b4 = *(const float4*)(rowB + jq * 4);
        float aAv[4] = {a4.x, a4.y, a4.z, a4.w};
        float aBv[4] = {b4.x, b4.y, b4.z, b4.w};
#pragma unroll
        for (int jj = 0; jj < 4; ++jj) {
            const float4* w = (const float4*)(Wr1 + (H + jq * 4 + jj) * H + k0);
            float4 w0 = w[0], w1 = w[1];
            FMA8V(w0, w1, aAv[jj], accA);
            FMA8V(w0, w1, aBv[jj], accB);
        }
    }
    {
        float rA[8], rB[8];
#pragma unroll
        for (int i = 0; i < 8; ++i) {
            rA[i] = fmaxf(accA[i], 0.f);
            rB[i] = fmaxf(accB[i], 0.f);
        }
        STORE8(rowA + k0, rA);
        STORE8(rowB + k0, rB);
    }

    // logits = r2 @ Wr2 + br2
    LOAD8(br2 + k0, accA);
#pragma unroll
    for (int i = 0; i < 8; ++i) accB[i] = accA[i];
#pragma unroll 4
    for (int jq = 0; jq < 16; ++jq) {
        float4 a4 = *(const float4*)(rowA + jq * 4);
        float4 b4 = *(const float4*)(rowB + jq * 4);
        float aAv[4] = {a4.x, a4.y, a4.z, a4.w};
        float aBv[4] = {b4.x, b4.y, b4.z, b4.w};
#pragma unroll
        for (int jj = 0; jj < 4; ++jj) {
            const float4* w = (const float4*)(Wr2 + (jq * 4 + jj) * H + k0);
            float4 w0 = w[0], w1 = w[1];
            FMA8V(w0, w1, aAv[jj], accA);
            FMA8V(w0, w1, aBv[jj], accB);
        }
    }

    float4* oA = (float4*)(out + (size_t)gidA * H + k0);
    oA[0] = make_float4(accA[0], accA[1], accA[2], accA[3]);
    oA[1] = make_float4(accA[4], accA[5], accA[6], accA[7]);
    float4* oB = (float4*)(out + (size_t)gidB * H + k0);
    oB[0] = make_float4(accB[0], accB[1], accB[2], accB[3]);
    oB[1] = make_float4(accB[4], accB[5], accB[6], accB[7]);
}

extern "C" void kernel_launch(void* const* d_in, const int* in_sizes, int n_in,
                              void* d_out, int out_size, void* d_ws, size_t ws_size,
                              hipStream_t stream)
{
    const int*   seqs  = (const int*)d_in[0];
    const int*   qtok  = (const int*)d_in[1];
    const float* embed = (const float*)d_in[2];
    const float* W1    = (const float*)d_in[3];
    const float* b1    = (const float*)d_in[4];
    const float* W2    = (const float*)d_in[5];
    const float* b2    = (const float*)d_in[6];
    const float* Ww    = (const float*)d_in[7];
    const float* bw    = (const float*)d_in[8];
    const float* We    = (const float*)d_in[9];
    const float* be    = (const float*)d_in[10];
    const float* Wr1   = (const float*)d_in[11];
    const float* br1   = (const float*)d_in[12];
    const float* Wr2   = (const float*)d_in[13];
    const float* br2   = (const float*)d_in[14];
    float* out = (float*)d_out;
    float* ws  = (float*)d_ws;

    hipLaunchKernelGGL(k_setup_tables, dim3((NV * H + 255) / 256), dim3(256), 0, stream,
                       embed, W1, b1, Wr1, br1, ws);
    hipLaunchKernelGGL(k_setup_fuse, dim3((NSLOT * H * H + NSLOT * H + 255) / 256), dim3(256),
                       0, stream, W1, Ww, bw, ws);
    hipLaunchKernelGGL(k_main, dim3(NB / EPB), dim3(TPB), 0, stream,
                       W2, b2, Ww, bw, We, be, Wr1, Wr2, br2, qtok, seqs,
                       ws, ws + OFF_HL, out);
}

// Round 7
// 1102.558 us; speedup vs baseline: 1.1383x; 1.0098x over previous
//
#include <hip/hip_runtime.h>

#define H       64
#define NSLOT   4
#define NSTEP   23          // SEQ_LEN - 1
#define NB      65536
#define NV      66          // VOCAB_SIZE + 2
#define SEQL    24
#define LPE     8           // lanes per element
#define TPB     512         // 8 waves
#define EPB     256         // G=4: four elements per lane, two staggered pairs
#define ACTSTR  68          // act row stride: conflict-free b128 broadcast reads
#define MROW    68          // sM row stride
#define JL      48          // M rows j<JL from LDS; j>=JL from global (R0-proven balance)
#define MSSTR   (JL * MROW + 4)   // 48*68+4=3268 ; 3268%32==4 (bank-offset invariant)

// R6 post-mortem: staggering SINGLE elements doubled W2 VMEM (lost A/B sharing)
// and serialized the per-phase chains -> 1113us. R7 staggers PAIRS: each phase
// runs PV(pair0) [DS, 2 indep chains] fused with W2(pair1) [VMEM, shared row
// loads, 2 indep chains] in ONE basic block -> both pipes fed, sharing kept,
// 4 FMA chains/phase. Occupancy is hard-capped at 8 waves/CU (R4/R5), so LDS
// 124KB is free. Per-CU DS/VMEM/VALU totals identical to R0; lever = overlap.

// ---- workspace layout (float offsets) ----
#define OFF_EW1   0                  // embW1b  [NV][H] = embed@W1[:64] + b1
#define OFF_EWR1  (NV * H)           // embWr1b [NV][H] = embed@Wr1[:64] + br1
#define OFF_M     (2 * NV * H)       // M [4][64][64] = Ww @ W1slot_s
#define OFF_PB    (OFF_M + NSLOT * H * H)   // pb [4][64] = bw @ W1slot_s
#define OFF_HL    (OFF_PB + NSLOT * H)      // hlast [NB][4][64]  (64 MB)

__global__ __launch_bounds__(256) void k_setup_tables(
    const float* __restrict__ embed, const float* __restrict__ W1, const float* __restrict__ b1,
    const float* __restrict__ Wr1, const float* __restrict__ br1, float* __restrict__ ws)
{
    int idx = blockIdx.x * 256 + threadIdx.x;
    if (idx >= NV * H) return;
    int t = idx >> 6, k = idx & 63;
    float a1 = b1[k], a2 = br1[k];
    for (int j = 0; j < H; ++j) {
        float e = embed[t * H + j];
        a1 = fmaf(e, W1[j * H + k], a1);
        a2 = fmaf(e, Wr1[j * H + k], a2);
    }
    ws[OFF_EW1 + idx]  = a1;
    ws[OFF_EWR1 + idx] = a2;
}

__global__ __launch_bounds__(256) void k_setup_fuse(
    const float* __restrict__ W1, const float* __restrict__ Ww, const float* __restrict__ bw,
    float* __restrict__ ws)
{
    int idx = blockIdx.x * 256 + threadIdx.x;
    if (idx < NSLOT * H * H) {
        int s = idx >> 12, j = (idx >> 6) & 63, k = idx & 63;
        const float* w1s = W1 + (size_t)(H + s * H) * H;   // [p][k]
        float acc = 0.f;
        for (int p = 0; p < H; ++p)
            acc = fmaf(Ww[j * H + p], w1s[p * H + k], acc);
        ws[OFF_M + idx] = acc;
    } else if (idx < NSLOT * H * H + NSLOT * H) {
        int r = idx - NSLOT * H * H;
        int s = r >> 6, k = r & 63;
        const float* w1s = W1 + (size_t)(H + s * H) * H;
        float acc = 0.f;
        for (int p = 0; p < H; ++p)
            acc = fmaf(bw[p], w1s[p * H + k], acc);
        ws[OFF_PB + r] = acc;
    }
}

#define FMA8V(w0, w1, a, ACC) do {                                          \
    ACC[0]=fmaf((a),w0.x,ACC[0]); ACC[1]=fmaf((a),w0.y,ACC[1]);            \
    ACC[2]=fmaf((a),w0.z,ACC[2]); ACC[3]=fmaf((a),w0.w,ACC[3]);            \
    ACC[4]=fmaf((a),w1.x,ACC[4]); ACC[5]=fmaf((a),w1.y,ACC[5]);            \
    ACC[6]=fmaf((a),w1.z,ACC[6]); ACC[7]=fmaf((a),w1.w,ACC[7]);            \
} while (0)

#define LOAD8(ptr, A) do {                                                  \
    const float4* _b = (const float4*)(ptr);                                \
    float4 _b0 = _b[0], _b1 = _b[1];                                        \
    A[0]=_b0.x; A[1]=_b0.y; A[2]=_b0.z; A[3]=_b0.w;                        \
    A[4]=_b1.x; A[5]=_b1.y; A[6]=_b1.z; A[7]=_b1.w;                        \
} while (0)

#define STORE8(rowptr, A) do {                                              \
    float4* _d = (float4*)(rowptr);                                         \
    _d[0] = make_float4(A[0], A[1], A[2], A[3]);                            \
    _d[1] = make_float4(A[4], A[5], A[6], A[7]);                            \
} while (0)

// W2 matvec for a lockstep pair: shared weight loads, 2 independent acc chains.
__device__ __forceinline__ void w2_pair(const float* rowX, const float* rowY,
    const float* W2k, float accX[8], float accY[8])
{
#pragma unroll 4
    for (int jq = 0; jq < 16; ++jq) {
        float4 x4 = *(const float4*)(rowX + jq * 4);
        float4 y4 = *(const float4*)(rowY + jq * 4);
        float xv[4] = {x4.x, x4.y, x4.z, x4.w};
        float yv[4] = {y4.x, y4.y, y4.z, y4.w};
#pragma unroll
        for (int jj = 0; jj < 4; ++jj) {
            const float4* wp = (const float4*)(W2k + (jq * 4 + jj) * H);
            float4 w0 = wp[0], w1 = wp[1];
            FMA8V(w0, w1, xv[jj], accX);
            FMA8V(w0, w1, yv[jj], accY);
        }
    }
}

// Fused phase: PV for pair {P,Q} (DS rows j<JL + global rows j>=JL, per-element
// matrices) ∥ W2 for pair {X,Y} (shared VMEM rows). One basic block, 4 chains.
__device__ __forceinline__ void pv2_w2_pair(
    const float* rowP, const float* rowQ, const float* rowX, const float* rowY,
    const float* lMP, const float* gMP,
    const float* lMQ, const float* gMQ,
    const float* W2k,
    float accP[8], float accQ[8], float accX[8], float accY[8])
{
#pragma unroll 2
    for (int jq = 0; jq < JL / 4; ++jq) {
        float4 p4 = *(const float4*)(rowP + jq * 4);
        float4 q4 = *(const float4*)(rowQ + jq * 4);
        float4 x4 = *(const float4*)(rowX + jq * 4);
        float4 y4 = *(const float4*)(rowY + jq * 4);
        float pv[4] = {p4.x, p4.y, p4.z, p4.w};
        float qv[4] = {q4.x, q4.y, q4.z, q4.w};
        float xv[4] = {x4.x, x4.y, x4.z, x4.w};
        float yv[4] = {y4.x, y4.y, y4.z, y4.w};
#pragma unroll
        for (int jj = 0; jj < 4; ++jj) {
            int j = jq * 4 + jj;
            const float4* mp = (const float4*)(lMP + j * MROW);
            const float4* mq = (const float4*)(lMQ + j * MROW);
            const float4* wp = (const float4*)(W2k + j * H);
            float4 mp0 = mp[0], mp1 = mp[1];
            float4 mq0 = mq[0], mq1 = mq[1];
            float4 w0 = wp[0], w1 = wp[1];
            FMA8V(mp0, mp1, pv[jj], accP);
            FMA8V(mq0, mq1, qv[jj], accQ);
            FMA8V(w0, w1, xv[jj], accX);
            FMA8V(w0, w1, yv[jj], accY);
        }
    }
#pragma unroll 2
    for (int jq = JL / 4; jq < 16; ++jq) {
        float4 p4 = *(const float4*)(rowP + jq * 4);
        float4 q4 = *(const float4*)(rowQ + jq * 4);
        float4 x4 = *(const float4*)(rowX + jq * 4);
        float4 y4 = *(const float4*)(rowY + jq * 4);
        float pv[4] = {p4.x, p4.y, p4.z, p4.w};
        float qv[4] = {q4.x, q4.y, q4.z, q4.w};
        float xv[4] = {x4.x, x4.y, x4.z, x4.w};
        float yv[4] = {y4.x, y4.y, y4.z, y4.w};
#pragma unroll
        for (int jj = 0; jj < 4; ++jj) {
            int j = jq * 4 + jj;
            const float4* mp = (const float4*)(gMP + (j - JL) * H);
            const float4* mq = (const float4*)(gMQ + (j - JL) * H);
            const float4* wp = (const float4*)(W2k + j * H);
            float4 mp0 = mp[0], mp1 = mp[1];
            float4 mq0 = mq[0], mq1 = mq[1];
            float4 w0 = wp[0], w1 = wp[1];
            FMA8V(mp0, mp1, pv[jj], accP);
            FMA8V(mq0, mq1, qv[jj], accQ);
            FMA8V(w0, w1, xv[jj], accX);
            FMA8V(w0, w1, yv[jj], accY);
        }
    }
}

// 4-element matvec with 4-way shared weight loads (tail only).
__device__ __forceinline__ void mv4_shared(
    const float* rowA, const float* rowB, const float* rowC, const float* rowD,
    const float* Wk, float aA[8], float aB[8], float aC[8], float aD[8])
{
#pragma unroll 4
    for (int jq = 0; jq < 16; ++jq) {
        float4 a4 = *(const float4*)(rowA + jq * 4);
        float4 b4 = *(const float4*)(rowB + jq * 4);
        float4 c4 = *(const float4*)(rowC + jq * 4);
        float4 d4 = *(const float4*)(rowD + jq * 4);
        float av[4] = {a4.x, a4.y, a4.z, a4.w};
        float bv[4] = {b4.x, b4.y, b4.z, b4.w};
        float cv[4] = {c4.x, c4.y, c4.z, c4.w};
        float dv[4] = {d4.x, d4.y, d4.z, d4.w};
#pragma unroll
        for (int jj = 0; jj < 4; ++jj) {
            const float4* wp = (const float4*)(Wk + (jq * 4 + jj) * H);
            float4 w0 = wp[0], w1 = wp[1];
            FMA8V(w0, w1, av[jj], aA);
            FMA8V(w0, w1, bv[jj], aB);
            FMA8V(w0, w1, cv[jj], aC);
            FMA8V(w0, w1, dv[jj], aD);
        }
    }
}

__device__ __forceinline__ int evict_sel(const float h2[8], const float* wsl, float4 be4)
{
    float l0 = 0.f, l1 = 0.f, l2 = 0.f, l3 = 0.f;
#pragma unroll
    for (int i = 0; i < 8; ++i) {
        float4 we4 = *(const float4*)(wsl + i * 4);
        l0 = fmaf(h2[i], we4.x, l0); l1 = fmaf(h2[i], we4.y, l1);
        l2 = fmaf(h2[i], we4.z, l2); l3 = fmaf(h2[i], we4.w, l3);
    }
#pragma unroll
    for (int d = 1; d <= 4; d <<= 1) {
        l0 += __shfl_xor(l0, d); l1 += __shfl_xor(l1, d);
        l2 += __shfl_xor(l2, d); l3 += __shfl_xor(l3, d);
    }
    l0 += be4.x; l1 += be4.y; l2 += be4.z; l3 += be4.w;
    int e = 0; float b = l0;                       // first-max wins = jnp.argmax
    if (l1 > b) { b = l1; e = 1; }
    if (l2 > b) { b = l2; e = 2; }
    if (l3 > b) { b = l3; e = 3; }
    return e;
}

__device__ __forceinline__ void upd_contrib(int eS, const float pv[8], float c[8],
                                            float p0[8], float p1[8], float p2[8], float p3[8])
{
    bool f0 = (eS == 0), f1 = (eS == 1), f2 = (eS == 2), f3 = (eS == 3);
#pragma unroll
    for (int i = 0; i < 8; ++i) {
        float v = pv[i];
        float old = f0 ? p0[i] : f1 ? p1[i] : f2 ? p2[i] : p3[i];
        c[i] += v - old;
        p0[i] = f0 ? v : p0[i]; p1[i] = f1 ? v : p1[i];
        p2[i] = f2 ? v : p2[i]; p3[i] = f3 ? v : p3[i];
    }
}

// h2 = relu(acc); store to act row; evict select; hlast store; mask update.
__device__ __forceinline__ int h2_finish(const float accW[8], float* row, int k0,
    const float* wsl, float4 be4, float* hlE, int& mask)
{
    float h2[8];
#pragma unroll
    for (int i = 0; i < 8; ++i) h2[i] = fmaxf(accW[i], 0.f);
    STORE8(row + k0, h2);
    int eS = evict_sel(h2, wsl, be4);
    STORE8(hlE + eS * H, h2);
    mask |= 1 << eS;
    return eS;
}

__device__ __forceinline__ void h1_store(const float* embrow, const float c[8],
                                         float* row, int k0)
{
    float h[8];
    LOAD8(embrow, h);
#pragma unroll
    for (int i = 0; i < 8; ++i) h[i] = fmaxf(h[i] + c[i], 0.f);
    STORE8(row + k0, h);
}

__global__ __launch_bounds__(TPB, 1) void k_main(
    const float* __restrict__ W2, const float* __restrict__ b2,
    const float* __restrict__ Ww, const float* __restrict__ bw,
    const float* __restrict__ We, const float* __restrict__ be,
    const float* __restrict__ Wr1, const float* __restrict__ Wr2, const float* __restrict__ br2,
    const int* __restrict__ qtok, const int* __restrict__ seqs,
    const float* __restrict__ ws, float* hl, float* __restrict__ out)
{
    __shared__ float sM[NSLOT * MSSTR];    // ~52.3 KB
    __shared__ float sAct[EPB * ACTSTR];   // 256 rows ~69.6 KB
    __shared__ float sPb[NSLOT * 68];
    __shared__ float sWeS[8 * 36];

    const int tid  = threadIdx.x;
    const int m    = tid & (LPE - 1);
    const int g    = tid >> 3;             // group 0..63
    const int eA   = g;
    const int eB   = g + 64;
    const int eC   = g + 128;
    const int eD   = g + 192;
    const int gidA = blockIdx.x * EPB + eA;
    const int gidB = blockIdx.x * EPB + eB;
    const int gidC = blockIdx.x * EPB + eC;
    const int gidD = blockIdx.x * EPB + eD;
    const int k0   = m * 8;

    // ---- stage LDS ----
    if (tid < 256) {
        int s = tid >> 6, j = tid & 63;
        if (j < JL) {
            const float4* src = (const float4*)(ws + OFF_M + (size_t)(s * H + j) * H);
            float4* dst = (float4*)(sM + s * MSSTR + j * MROW);
#pragma unroll
            for (int k = 0; k < 16; ++k) dst[k] = src[k];
        }
    }
    if (tid >= 256 && tid < 512) {
        int r = tid - 256;
        int s = r >> 6, k = r & 63;
        sPb[s * 68 + k] = ws[OFF_PB + s * H + k];
    }
    if (tid < 256) {
        int mm = tid >> 5, rem = tid & 31;
        sWeS[mm * 36 + rem] = We[tid];
    }
    __syncthreads();

    const float* embW1b  = ws + OFF_EW1;
    const float* embWr1b = ws + OFF_EWR1;
    const float* Mg      = ws + OFF_M;
    const float* W2k     = W2 + k0;
    const float* wsl     = sWeS + m * 36;
    float* hlA = hl + (size_t)gidA * (NSLOT * H) + k0;
    float* hlB = hl + (size_t)gidB * (NSLOT * H) + k0;
    float* hlC = hl + (size_t)gidC * (NSLOT * H) + k0;
    float* hlD = hl + (size_t)gidD * (NSLOT * H) + k0;

    float pA0[8], pA1[8], pA2[8], pA3[8], cA[8];
    float pB0[8], pB1[8], pB2[8], pB3[8], cB[8];
    float pC0[8], pC1[8], pC2[8], pC3[8], cC[8];
    float pD0[8], pD1[8], pD2[8], pD3[8], cD[8];
#pragma unroll
    for (int i = 0; i < 8; ++i) {
        pA0[i]=0.f; pA1[i]=0.f; pA2[i]=0.f; pA3[i]=0.f; cA[i]=0.f;
        pB0[i]=0.f; pB1[i]=0.f; pB2[i]=0.f; pB3[i]=0.f; cB[i]=0.f;
        pC0[i]=0.f; pC1[i]=0.f; pC2[i]=0.f; pC3[i]=0.f; cC[i]=0.f;
        pD0[i]=0.f; pD1[i]=0.f; pD2[i]=0.f; pD3[i]=0.f; cD[i]=0.f;
    }
    int maskA = 0, maskB = 0, maskC = 0, maskD = 0;

    float b2r[8];
    LOAD8(b2 + k0, b2r);
    const float4 be4 = *(const float4*)be;

    float* rowA = sAct + eA * ACTSTR;
    float* rowB = sAct + eB * ACTSTR;
    float* rowC = sAct + eC * ACTSTR;
    float* rowD = sAct + eD * ACTSTR;

    int eSA, eSB, eSC, eSD;

    // ---- prologue: P0 step 0 (plain W2 pair), P1 h1(0) ----
    {
        int tokA = seqs[gidA * SEQL], tokB = seqs[gidB * SEQL];
        h1_store(embW1b + tokA * H + k0, cA, rowA, k0);
        h1_store(embW1b + tokB * H + k0, cB, rowB, k0);
        float accWA[8], accWB[8];
#pragma unroll
        for (int i = 0; i < 8; ++i) { accWA[i] = b2r[i]; accWB[i] = b2r[i]; }
        w2_pair(rowA, rowB, W2k, accWA, accWB);
        eSA = h2_finish(accWA, rowA, k0, wsl, be4, hlA, maskA);
        eSB = h2_finish(accWB, rowB, k0, wsl, be4, hlB, maskB);
        int tokC = seqs[gidC * SEQL], tokD = seqs[gidD * SEQL];
        h1_store(embW1b + tokC * H + k0, cC, rowC, k0);
        h1_store(embW1b + tokD * H + k0, cD, rowD, k0);
    }

    // ---- main loop: X = PV(P0,t) ∥ W2(P1,t) ; Y = PV(P1,t) ∥ W2(P0,t+1) ----
#pragma unroll 1
    for (int t = 0; t < NSTEP - 1; ++t) {
        int tA1 = seqs[gidA * SEQL + t + 1];
        int tB1 = seqs[gidB * SEQL + t + 1];
        int tC1 = seqs[gidC * SEQL + t + 1];
        int tD1 = seqs[gidD * SEQL + t + 1];

        // phase X
        {
            float accPA[8], accPB[8], accWC[8], accWD[8];
            LOAD8(sPb + eSA * 68 + k0, accPA);
            LOAD8(sPb + eSB * 68 + k0, accPB);
#pragma unroll
            for (int i = 0; i < 8; ++i) { accWC[i] = b2r[i]; accWD[i] = b2r[i]; }
            pv2_w2_pair(rowA, rowB, rowC, rowD,
                        sM + eSA * MSSTR + k0, Mg + (size_t)(eSA * H + JL) * H + k0,
                        sM + eSB * MSSTR + k0, Mg + (size_t)(eSB * H + JL) * H + k0,
                        W2k, accPA, accPB, accWC, accWD);
            eSC = h2_finish(accWC, rowC, k0, wsl, be4, hlC, maskC);
            eSD = h2_finish(accWD, rowD, k0, wsl, be4, hlD, maskD);
            upd_contrib(eSA, accPA, cA, pA0, pA1, pA2, pA3);
            upd_contrib(eSB, accPB, cB, pB0, pB1, pB2, pB3);
            h1_store(embW1b + tA1 * H + k0, cA, rowA, k0);
            h1_store(embW1b + tB1 * H + k0, cB, rowB, k0);
        }

        // phase Y
        {
            float accPC[8], accPD[8], accWA[8], accWB[8];
            LOAD8(sPb + eSC * 68 + k0, accPC);
            LOAD8(sPb + eSD * 68 + k0, accPD);
#pragma unroll
            for (int i = 0; i < 8; ++i) { accWA[i] = b2r[i]; accWB[i] = b2r[i]; }
            pv2_w2_pair(rowC, rowD, rowA, rowB,
                        sM + eSC * MSSTR + k0, Mg + (size_t)(eSC * H + JL) * H + k0,
                        sM + eSD * MSSTR + k0, Mg + (size_t)(eSD * H + JL) * H + k0,
                        W2k, accPC, accPD, accWA, accWB);
            eSA = h2_finish(accWA, rowA, k0, wsl, be4, hlA, maskA);
            eSB = h2_finish(accWB, rowB, k0, wsl, be4, hlB, maskB);
            upd_contrib(eSC, accPC, cC, pC0, pC1, pC2, pC3);
            upd_contrib(eSD, accPD, cD, pD0, pD1, pD2, pD3);
            h1_store(embW1b + tC1 * H + k0, cC, rowC, k0);
            h1_store(embW1b + tD1 * H + k0, cD, rowD, k0);
        }
    }

    // ---- epilogue: P1 step 22 (plain W2 pair; final-step PV dead for all) ----
    {
        float accWC[8], accWD[8];
#pragma unroll
        for (int i = 0; i < 8; ++i) { accWC[i] = b2r[i]; accWD[i] = b2r[i]; }
        w2_pair(rowC, rowD, W2k, accWC, accWD);
        eSC = h2_finish(accWC, rowC, k0, wsl, be4, hlC, maskC);
        eSD = h2_finish(accWD, rowD, k0, wsl, be4, hlD, maskD);
    }

    // ---- tail: hsum = sum of surviving hlast slots ----
    __threadfence();
    float accA[8], accB[8], accC[8], accD[8];
    {
        float hsA[8] = {0,0,0,0,0,0,0,0}, hsB[8] = {0,0,0,0,0,0,0,0};
        float hsC[8] = {0,0,0,0,0,0,0,0}, hsD[8] = {0,0,0,0,0,0,0,0};
#pragma unroll
        for (int s = 0; s < NSLOT; ++s) {
            float vA[8], vB[8], vC[8], vD[8];
            LOAD8(hlA + s * H, vA);
            LOAD8(hlB + s * H, vB);
            LOAD8(hlC + s * H, vC);
            LOAD8(hlD + s * H, vD);
            float fA = ((maskA >> s) & 1) ? 1.f : 0.f;
            float fB = ((maskB >> s) & 1) ? 1.f : 0.f;
            float fC = ((maskC >> s) & 1) ? 1.f : 0.f;
            float fD = ((maskD >> s) & 1) ? 1.f : 0.f;
#pragma unroll
            for (int i = 0; i < 8; ++i) {
                hsA[i] = fmaf(fA, vA[i], hsA[i]);
                hsB[i] = fmaf(fB, vB[i], hsB[i]);
                hsC[i] = fmaf(fC, vC[i], hsC[i]);
                hsD[i] = fmaf(fD, vD[i], hsD[i]);
            }
        }
        STORE8(rowA + k0, hsA);
        STORE8(rowB + k0, hsB);
        STORE8(rowC + k0, hsC);
        STORE8(rowD + k0, hsD);
    }

    // msum = (hsum @ Ww + cnt*bw) / 4
    {
        float bwr[8];
        LOAD8(bw + k0, bwr);
        float nA = (float)__popc(maskA), nB = (float)__popc(maskB);
        float nC = (float)__popc(maskC), nD = (float)__popc(maskD);
#pragma unroll
        for (int i = 0; i < 8; ++i) {
            accA[i] = nA * bwr[i]; accB[i] = nB * bwr[i];
            accC[i] = nC * bwr[i]; accD[i] = nD * bwr[i];
        }
    }
    mv4_shared(rowA, rowB, rowC, rowD, Ww + k0, accA, accB, accC, accD);
    {
        float t[8];
#pragma unroll
        for (int i = 0; i < 8; ++i) t[i] = accA[i] * 0.25f;
        STORE8(rowA + k0, t);
#pragma unroll
        for (int i = 0; i < 8; ++i) t[i] = accB[i] * 0.25f;
        STORE8(rowB + k0, t);
#pragma unroll
        for (int i = 0; i < 8; ++i) t[i] = accC[i] * 0.25f;
        STORE8(rowC + k0, t);
#pragma unroll
        for (int i = 0; i < 8; ++i) t[i] = accD[i] * 0.25f;
        STORE8(rowD + k0, t);
    }

    // r2 = relu(embWr1b[q] + msum @ Wr1[64:128])
    {
        int qA = qtok[gidA], qB = qtok[gidB], qC = qtok[gidC], qD = qtok[gidD];
        LOAD8(embWr1b + qA * H + k0, accA);
        LOAD8(embWr1b + qB * H + k0, accB);
        LOAD8(embWr1b + qC * H + k0, accC);
        LOAD8(embWr1b + qD * H + k0, accD);
    }
    mv4_shared(rowA, rowB, rowC, rowD, Wr1 + (size_t)H * H + k0, accA, accB, accC, accD);
    {
        float t[8];
#pragma unroll
        for (int i = 0; i < 8; ++i) t[i] = fmaxf(accA[i], 0.f);
        STORE8(rowA + k0, t);
#pragma unroll
        for (int i = 0; i < 8; ++i) t[i] = fmaxf(accB[i], 0.f);
        STORE8(rowB + k0, t);
#pragma unroll
        for (int i = 0; i < 8; ++i) t[i] = fmaxf(accC[i], 0.f);
        STORE8(rowC + k0, t);
#pragma unroll
        for (int i = 0; i < 8; ++i) t[i] = fmaxf(accD[i], 0.f);
        STORE8(rowD + k0, t);
    }

    // logits = r2 @ Wr2 + br2
    LOAD8(br2 + k0, accA);
#pragma unroll
    for (int i = 0; i < 8; ++i) { accB[i] = accA[i]; accC[i] = accA[i]; accD[i] = accA[i]; }
    mv4_shared(rowA, rowB, rowC, rowD, Wr2 + k0, accA, accB, accC, accD);

    float4* oA = (float4*)(out + (size_t)gidA * H + k0);
    oA[0] = make_float4(accA[0], accA[1], accA[2], accA[3]);
    oA[1] = make_float4(accA[4], accA[5], accA[6], accA[7]);
    float4* oB = (float4*)(out + (size_t)gidB * H + k0);
    oB[0] = make_float4(accB[0], accB[1], accB[2], accB[3]);
    oB[1] = make_float4(accB[4], accB[5], accB[6], accB[7]);
    float4* oC = (float4*)(out + (size_t)gidC * H + k0);
    oC[0] = make_float4(accC[0], accC[1], accC[2], accC[3]);
    oC[1] = make_float4(accC[4], accC[5], accC[6], accC[7]);
    float4* oD = (float4*)(out + (size_t)gidD * H + k0);
    oD[0] = make_float4(accD[0], accD[1], accD[2], accD[3]);
    oD[1] = make_float4(accD[4], accD[5], accD[6], accD[7]);
}

extern "C" void kernel_launch(void* const* d_in, const int* in_sizes, int n_in,
                              void* d_out, int out_size, void* d_ws, size_t ws_size,
                              hipStream_t stream)
{
    const int*   seqs  = (const int*)d_in[0];
    const int*   qtok  = (const int*)d_in[1];
    const float* embed = (const float*)d_in[2];
    const float* W1    = (const float*)d_in[3];
    const float* b1    = (const float*)d_in[4];
    const float* W2    = (const float*)d_in[5];
    const float* b2    = (const float*)d_in[6];
    const float* Ww    = (const float*)d_in[7];
    const float* bw    = (const float*)d_in[8];
    const float* We    = (const float*)d_in[9];
    const float* be    = (const float*)d_in[10];
    const float* Wr1   = (const float*)d_in[11];
    const float* br1   = (const float*)d_in[12];
    const float* Wr2   = (const float*)d_in[13];
    const float* br2   = (const float*)d_in[14];
    float* out = (float*)d_out;
    float* ws  = (float*)d_ws;

    hipLaunchKernelGGL(k_setup_tables, dim3((NV * H + 255) / 256), dim3(256), 0, stream,
                       embed, W1, b1, Wr1, br1, ws);
    hipLaunchKernelGGL(k_setup_fuse, dim3((NSLOT * H * H + NSLOT * H + 255) / 256), dim3(256),
                       0, stream, W1, Ww, bw, ws);
    hipLaunchKernelGGL(k_main, dim3(NB / EPB), dim3(TPB), 0, stream,
                       W2, b2, Ww, bw, We, be, Wr1, Wr2, br2, qtok, seqs,
                       ws, ws + OFF_HL, out);
}

// Round 8
// 851.237 us; speedup vs baseline: 1.4744x; 1.2952x over previous
//
#include <hip/hip_runtime.h>

#define H       64
#define NSLOT   4
#define NSTEP   23          // SEQ_LEN - 1
#define NB      65536
#define NV      66          // VOCAB_SIZE + 2
#define SEQL    24
#define LPE     8           // lanes per element
#define TPB     512         // 8 waves
#define EPB     128         // elements per block (G=2 per lane)
#define ACTSTR  68          // act row stride: conflict-free b128 broadcast reads
#define MROW    68          // sM row stride
#define JL      64          // ALL M rows in LDS. R4 A/B (JL 48 vs 40, same VGPR/occ):
                            // each row moved LDS->global cost ~13us (L1 thrash + L2
                            // latency). Occupancy is hard-capped at 1 block/CU for
                            // VGPR>=88 (R4/R5), so LDS is free: 104KB < 160KB.
#define MSSTR   (JL * MROW + 4)   // 64*68+4=4356 ; 4356%32==4 (bank-offset invariant)

// ---- workspace layout (float offsets) ----
#define OFF_EW1   0                  // embW1b  [NV][H] = embed@W1[:64] + b1
#define OFF_EWR1  (NV * H)           // embWr1b [NV][H] = embed@Wr1[:64] + br1
#define OFF_M     (2 * NV * H)       // M [4][64][64] = Ww @ W1slot_s
#define OFF_PB    (OFF_M + NSLOT * H * H)   // pb [4][64] = bw @ W1slot_s
#define OFF_HL    (OFF_PB + NSLOT * H)      // hlast [NB][4][64]  (64 MB)

__global__ __launch_bounds__(256) void k_setup_tables(
    const float* __restrict__ embed, const float* __restrict__ W1, const float* __restrict__ b1,
    const float* __restrict__ Wr1, const float* __restrict__ br1, float* __restrict__ ws)
{
    int idx = blockIdx.x * 256 + threadIdx.x;
    if (idx >= NV * H) return;
    int t = idx >> 6, k = idx & 63;
    float a1 = b1[k], a2 = br1[k];
    for (int j = 0; j < H; ++j) {
        float e = embed[t * H + j];
        a1 = fmaf(e, W1[j * H + k], a1);
        a2 = fmaf(e, Wr1[j * H + k], a2);
    }
    ws[OFF_EW1 + idx]  = a1;
    ws[OFF_EWR1 + idx] = a2;
}

__global__ __launch_bounds__(256) void k_setup_fuse(
    const float* __restrict__ W1, const float* __restrict__ Ww, const float* __restrict__ bw,
    float* __restrict__ ws)
{
    int idx = blockIdx.x * 256 + threadIdx.x;
    if (idx < NSLOT * H * H) {
        int s = idx >> 12, j = (idx >> 6) & 63, k = idx & 63;
        const float* w1s = W1 + (size_t)(H + s * H) * H;   // [p][k]
        float acc = 0.f;
        for (int p = 0; p < H; ++p)
            acc = fmaf(Ww[j * H + p], w1s[p * H + k], acc);
        ws[OFF_M + idx] = acc;
    } else if (idx < NSLOT * H * H + NSLOT * H) {
        int r = idx - NSLOT * H * H;
        int s = r >> 6, k = r & 63;
        const float* w1s = W1 + (size_t)(H + s * H) * H;
        float acc = 0.f;
        for (int p = 0; p < H; ++p)
            acc = fmaf(bw[p], w1s[p * H + k], acc);
        ws[OFF_PB + r] = acc;
    }
}

#define FMA8V(w0, w1, a, ACC) do {                                          \
    ACC[0]=fmaf((a),w0.x,ACC[0]); ACC[1]=fmaf((a),w0.y,ACC[1]);            \
    ACC[2]=fmaf((a),w0.z,ACC[2]); ACC[3]=fmaf((a),w0.w,ACC[3]);            \
    ACC[4]=fmaf((a),w1.x,ACC[4]); ACC[5]=fmaf((a),w1.y,ACC[5]);            \
    ACC[6]=fmaf((a),w1.z,ACC[6]); ACC[7]=fmaf((a),w1.w,ACC[7]);            \
} while (0)

#define LOAD8(ptr, A) do {                                                  \
    const float4* _b = (const float4*)(ptr);                                \
    float4 _b0 = _b[0], _b1 = _b[1];                                        \
    A[0]=_b0.x; A[1]=_b0.y; A[2]=_b0.z; A[3]=_b0.w;                        \
    A[4]=_b1.x; A[5]=_b1.y; A[6]=_b1.z; A[7]=_b1.w;                        \
} while (0)

#define STORE8(rowptr, A) do {                                              \
    float4* _d = (float4*)(rowptr);                                         \
    _d[0] = make_float4(A[0], A[1], A[2], A[3]);                            \
    _d[1] = make_float4(A[4], A[5], A[6], A[7]);                            \
} while (0)

__global__ __launch_bounds__(TPB, 1) void k_main(
    const float* __restrict__ W2, const float* __restrict__ b2,
    const float* __restrict__ Ww, const float* __restrict__ bw,
    const float* __restrict__ We, const float* __restrict__ be,
    const float* __restrict__ Wr1, const float* __restrict__ Wr2, const float* __restrict__ br2,
    const int* __restrict__ qtok, const int* __restrict__ seqs,
    const float* __restrict__ ws, float* hl, float* __restrict__ out)
{
    __shared__ float sM[NSLOT * MSSTR];    // all 64 M rows per slot  ~69.7 KB
    __shared__ float sAct[EPB * ACTSTR];   // [elem][j] rows, b128 broadcast reads ~35 KB
    __shared__ float sPb[NSLOT * 68];      // pb_s rows
    __shared__ float sWeS[8 * 36];         // per-chunk We slices [m][i*4+s]

    const int tid  = threadIdx.x;
    const int m    = tid & (LPE - 1);
    const int g    = tid >> 3;             // element group 0..63 (8 lanes, same wave)
    const int eA   = g;
    const int eB   = g + 64;
    const int gidA = blockIdx.x * EPB + eA;
    const int gidB = blockIdx.x * EPB + eB;
    const int k0   = m * 8;

    // ---- stage LDS ----
    if (tid < 256) {                        // sM: all 64 rows of each slot
        int s = tid >> 6, j = tid & 63;
        const float4* src = (const float4*)(ws + OFF_M + (size_t)(s * H + j) * H);
        float4* dst = (float4*)(sM + s * MSSTR + j * MROW);
#pragma unroll
        for (int k = 0; k < 16; ++k) dst[k] = src[k];
    }
    if (tid >= 256 && tid < 512) {
        int r = tid - 256;                  // sPb: 4 x 64
        int s = r >> 6, k = r & 63;
        sPb[s * 68 + k] = ws[OFF_PB + s * H + k];
    }
    if (tid < 256) {
        int mm = tid >> 5, rem = tid & 31;  // sWeS[m][i*4+s] = We[(m*8+i)*4+s]
        sWeS[mm * 36 + rem] = We[tid];
    }
    __syncthreads();

    const float* embW1b  = ws + OFF_EW1;
    const float* embWr1b = ws + OFF_EWR1;
    float* hlA = hl + (size_t)gidA * (NSLOT * H) + k0;
    float* hlB = hl + (size_t)gidB * (NSLOT * H) + k0;

    // register state per element: pmem 4x8 + contrib 8 + written-mask
    float pA0[8], pA1[8], pA2[8], pA3[8], cA[8];
    float pB0[8], pB1[8], pB2[8], pB3[8], cB[8];
#pragma unroll
    for (int i = 0; i < 8; ++i) {
        pA0[i]=0.f; pA1[i]=0.f; pA2[i]=0.f; pA3[i]=0.f; cA[i]=0.f;
        pB0[i]=0.f; pB1[i]=0.f; pB2[i]=0.f; pB3[i]=0.f; cB[i]=0.f;
    }
    int maskA = 0, maskB = 0;

    float b2r[8];
    LOAD8(b2 + k0, b2r);
    const float4 be4 = *(const float4*)be;

    int tokA = seqs[gidA * SEQL];
    int tokB = seqs[gidB * SEQL];

    float accA[8], accB[8];
    float* rowA = sAct + eA * ACTSTR;
    float* rowB = sAct + eB * ACTSTR;

#pragma unroll 1
    for (int t = 0; t < NSTEP - 1; ++t) {   // last step handled in epilogue (PV dead)
        int tokAn = seqs[gidA * SEQL + t + 1];
        int tokBn = seqs[gidB * SEQL + t + 1];

        // h1 = relu(embW1b[tok] + contrib) -> act rows
        {
            float hA[8], hB[8];
            LOAD8(embW1b + tokA * H + k0, hA);
            LOAD8(embW1b + tokB * H + k0, hB);
#pragma unroll
            for (int i = 0; i < 8; ++i) {
                hA[i] = fmaxf(hA[i] + cA[i], 0.f);
                hB[i] = fmaxf(hB[i] + cB[i], 0.f);
            }
            STORE8(rowA + k0, hA);
            STORE8(rowB + k0, hB);
        }

        // h2 = relu(h1 @ W2 + b2)   (W2 via VMEM; act b128 LDS broadcast)
#pragma unroll
        for (int i = 0; i < 8; ++i) { accA[i] = b2r[i]; accB[i] = b2r[i]; }
#pragma unroll 4
        for (int jq = 0; jq < 16; ++jq) {
            float4 a4 = *(const float4*)(rowA + jq * 4);
            float4 b4 = *(const float4*)(rowB + jq * 4);
            float aAv[4] = {a4.x, a4.y, a4.z, a4.w};
            float aBv[4] = {b4.x, b4.y, b4.z, b4.w};
#pragma unroll
            for (int jj = 0; jj < 4; ++jj) {
                const float4* w = (const float4*)(W2 + (jq * 4 + jj) * H + k0);
                float4 w0 = w[0], w1 = w[1];
                FMA8V(w0, w1, aAv[jj], accA);
                FMA8V(w0, w1, aBv[jj], accB);
            }
        }
        float h2A[8], h2B[8];
#pragma unroll
        for (int i = 0; i < 8; ++i) {
            h2A[i] = fmaxf(accA[i], 0.f);
            h2B[i] = fmaxf(accB[i], 0.f);
        }
        STORE8(rowA + k0, h2A);
        STORE8(rowB + k0, h2B);

        // evict logits in-register, then 8-lane butterfly sum
        float lA0 = 0.f, lA1 = 0.f, lA2 = 0.f, lA3 = 0.f;
        float lB0 = 0.f, lB1 = 0.f, lB2 = 0.f, lB3 = 0.f;
        {
            const float* wsl = sWeS + m * 36;
#pragma unroll
            for (int i = 0; i < 8; ++i) {
                float4 we4 = *(const float4*)(wsl + i * 4);
                lA0 = fmaf(h2A[i], we4.x, lA0); lA1 = fmaf(h2A[i], we4.y, lA1);
                lA2 = fmaf(h2A[i], we4.z, lA2); lA3 = fmaf(h2A[i], we4.w, lA3);
                lB0 = fmaf(h2B[i], we4.x, lB0); lB1 = fmaf(h2B[i], we4.y, lB1);
                lB2 = fmaf(h2B[i], we4.z, lB2); lB3 = fmaf(h2B[i], we4.w, lB3);
            }
        }
#pragma unroll
        for (int d = 1; d <= 4; d <<= 1) {
            lA0 += __shfl_xor(lA0, d); lA1 += __shfl_xor(lA1, d);
            lA2 += __shfl_xor(lA2, d); lA3 += __shfl_xor(lA3, d);
            lB0 += __shfl_xor(lB0, d); lB1 += __shfl_xor(lB1, d);
            lB2 += __shfl_xor(lB2, d); lB3 += __shfl_xor(lB3, d);
        }
        lA0 += be4.x; lA1 += be4.y; lA2 += be4.z; lA3 += be4.w;
        lB0 += be4.x; lB1 += be4.y; lB2 += be4.z; lB3 += be4.w;

        int eSA = 0; float bstA = lA0;               // first-max wins = jnp.argmax
        if (lA1 > bstA) { bstA = lA1; eSA = 1; }
        if (lA2 > bstA) { bstA = lA2; eSA = 2; }
        if (lA3 > bstA) { bstA = lA3; eSA = 3; }
        int eSB = 0; float bstB = lB0;
        if (lB1 > bstB) { bstB = lB1; eSB = 1; }
        if (lB2 > bstB) { bstB = lB2; eSB = 2; }
        if (lB3 > bstB) { bstB = lB3; eSB = 3; }

        bool a0 = (eSA == 0), a1 = (eSA == 1), a2 = (eSA == 2), a3 = (eSA == 3);
        bool b0 = (eSB == 0), b1 = (eSB == 1), b2_ = (eSB == 2), b3 = (eSB == 3);

        // hlast[e] <- h2  (global, fire-and-forget; read back only at tail)
        STORE8(hlA + eSA * H, h2A);
        STORE8(hlB + eSB * H, h2B);
        maskA |= (1 << eSA);
        maskB |= (1 << eSB);

        // pv = h2 @ M_e + pb_e   — all 64 rows from LDS (JL=64)
        LOAD8(sPb + eSA * 68 + k0, accA);
        LOAD8(sPb + eSB * 68 + k0, accB);
        const float* lMA = sM + eSA * MSSTR + k0;
        const float* lMB = sM + eSB * MSSTR + k0;
#pragma unroll 4
        for (int jq = 0; jq < 16; ++jq) {
            float4 a4 = *(const float4*)(rowA + jq * 4);
            float4 b4 = *(const float4*)(rowB + jq * 4);
            float dAv[4] = {a4.x, a4.y, a4.z, a4.w};
            float dBv[4] = {b4.x, b4.y, b4.z, b4.w};
#pragma unroll
            for (int jj = 0; jj < 4; ++jj) {
                int j = jq * 4 + jj;
                const float4* wa = (const float4*)(lMA + j * MROW);
                const float4* wb = (const float4*)(lMB + j * MROW);
                float4 wa0 = wa[0], wa1 = wa[1];
                float4 wb0 = wb[0], wb1 = wb[1];
                FMA8V(wa0, wa1, dAv[jj], accA);
                FMA8V(wb0, wb1, dBv[jj], accB);
            }
        }

        // contrib += pv - pmem[e] ; pmem[e] = pv
#pragma unroll
        for (int i = 0; i < 8; ++i) {
            float pvA = accA[i], pvB = accB[i];
            float oldA = a0 ? pA0[i] : a1 ? pA1[i] : a2 ? pA2[i] : pA3[i];
            float oldB = b0 ? pB0[i] : b1 ? pB1[i] : b2_ ? pB2[i] : pB3[i];
            cA[i] += pvA - oldA;
            cB[i] += pvB - oldB;
            pA0[i] = a0 ? pvA : pA0[i];  pA1[i] = a1 ? pvA : pA1[i];
            pA2[i] = a2 ? pvA : pA2[i];  pA3[i] = a3 ? pvA : pA3[i];
            pB0[i] = b0 ? pvB : pB0[i];  pB1[i] = b1 ? pvB : pB1[i];
            pB2[i] = b2_ ? pvB : pB2[i]; pB3[i] = b3 ? pvB : pB3[i];
        }

        tokA = tokAn; tokB = tokBn;
    }

    // ---- epilogue step t = NSTEP-1: h1/W2/evict/hlast only (PV+contrib dead) ----
    {
        float hA[8], hB[8];
        LOAD8(embW1b + tokA * H + k0, hA);
        LOAD8(embW1b + tokB * H + k0, hB);
#pragma unroll
        for (int i = 0; i < 8; ++i) {
            hA[i] = fmaxf(hA[i] + cA[i], 0.f);
            hB[i] = fmaxf(hB[i] + cB[i], 0.f);
        }
        STORE8(rowA + k0, hA);
        STORE8(rowB + k0, hB);

#pragma unroll
        for (int i = 0; i < 8; ++i) { accA[i] = b2r[i]; accB[i] = b2r[i]; }
#pragma unroll 4
        for (int jq = 0; jq < 16; ++jq) {
            float4 a4 = *(const float4*)(rowA + jq * 4);
            float4 b4 = *(const float4*)(rowB + jq * 4);
            float aAv[4] = {a4.x, a4.y, a4.z, a4.w};
            float aBv[4] = {b4.x, b4.y, b4.z, b4.w};
#pragma unroll
            for (int jj = 0; jj < 4; ++jj) {
                const float4* w = (const float4*)(W2 + (jq * 4 + jj) * H + k0);
                float4 w0 = w[0], w1 = w[1];
                FMA8V(w0, w1, aAv[jj], accA);
                FMA8V(w0, w1, aBv[jj], accB);
            }
        }
        float h2A[8], h2B[8];
#pragma unroll
        for (int i = 0; i < 8; ++i) {
            h2A[i] = fmaxf(accA[i], 0.f);
            h2B[i] = fmaxf(accB[i], 0.f);
        }

        float lA0 = 0.f, lA1 = 0.f, lA2 = 0.f, lA3 = 0.f;
        float lB0 = 0.f, lB1 = 0.f, lB2 = 0.f, lB3 = 0.f;
        {
            const float* wsl = sWeS + m * 36;
#pragma unroll
            for (int i = 0; i < 8; ++i) {
                float4 we4 = *(const float4*)(wsl + i * 4);
                lA0 = fmaf(h2A[i], we4.x, lA0); lA1 = fmaf(h2A[i], we4.y, lA1);
                lA2 = fmaf(h2A[i], we4.z, lA2); lA3 = fmaf(h2A[i], we4.w, lA3);
                lB0 = fmaf(h2B[i], we4.x, lB0); lB1 = fmaf(h2B[i], we4.y, lB1);
                lB2 = fmaf(h2B[i], we4.z, lB2); lB3 = fmaf(h2B[i], we4.w, lB3);
            }
        }
#pragma unroll
        for (int d = 1; d <= 4; d <<= 1) {
            lA0 += __shfl_xor(lA0, d); lA1 += __shfl_xor(lA1, d);
            lA2 += __shfl_xor(lA2, d); lA3 += __shfl_xor(lA3, d);
            lB0 += __shfl_xor(lB0, d); lB1 += __shfl_xor(lB1, d);
            lB2 += __shfl_xor(lB2, d); lB3 += __shfl_xor(lB3, d);
        }
        lA0 += be4.x; lA1 += be4.y; lA2 += be4.z; lA3 += be4.w;
        lB0 += be4.x; lB1 += be4.y; lB2 += be4.z; lB3 += be4.w;

        int eSA = 0; float bstA = lA0;
        if (lA1 > bstA) { bstA = lA1; eSA = 1; }
        if (lA2 > bstA) { bstA = lA2; eSA = 2; }
        if (lA3 > bstA) { bstA = lA3; eSA = 3; }
        int eSB = 0; float bstB = lB0;
        if (lB1 > bstB) { bstB = lB1; eSB = 1; }
        if (lB2 > bstB) { bstB = lB2; eSB = 2; }
        if (lB3 > bstB) { bstB = lB3; eSB = 3; }

        STORE8(hlA + eSA * H, h2A);
        STORE8(hlB + eSB * H, h2B);
        maskA |= (1 << eSA);
        maskB |= (1 << eSB);
    }

    // ---- tail: hsum = sum of surviving hlast slots (read back from global) ----
    __threadfence();   // drain hlast stores before read-back
    {
        float hsA[8] = {0,0,0,0,0,0,0,0}, hsB[8] = {0,0,0,0,0,0,0,0};
#pragma unroll
        for (int s = 0; s < NSLOT; ++s) {
            float vA[8], vB[8];
            LOAD8(hlA + s * H, vA);
            LOAD8(hlB + s * H, vB);
            float fA = ((maskA >> s) & 1) ? 1.f : 0.f;
            float fB = ((maskB >> s) & 1) ? 1.f : 0.f;
#pragma unroll
            for (int i = 0; i < 8; ++i) {
                hsA[i] = fmaf(fA, vA[i], hsA[i]);
                hsB[i] = fmaf(fB, vB[i], hsB[i]);
            }
        }
        STORE8(rowA + k0, hsA);
        STORE8(rowB + k0, hsB);
    }

    // msum = (hsum @ Ww + cnt*bw) / 4
    {
        float bwr[8];
        LOAD8(bw + k0, bwr);
        float cntA = (float)__popc(maskA), cntB = (float)__popc(maskB);
#pragma unroll
        for (int i = 0; i < 8; ++i) { accA[i] = cntA * bwr[i]; accB[i] = cntB * bwr[i]; }
    }
#pragma unroll 4
    for (int jq = 0; jq < 16; ++jq) {
        float4 a4 = *(const float4*)(rowA + jq * 4);
        float4 b4 = *(const float4*)(rowB + jq * 4);
        float aAv[4] = {a4.x, a4.y, a4.z, a4.w};
        float aBv[4] = {b4.x, b4.y, b4.z, b4.w};
#pragma unroll
        for (int jj = 0; jj < 4; ++jj) {
            const float4* w = (const float4*)(Ww + (jq * 4 + jj) * H + k0);
            float4 w0 = w[0], w1 = w[1];
            FMA8V(w0, w1, aAv[jj], accA);
            FMA8V(w0, w1, aBv[jj], accB);
        }
    }
    {
        float msA[8], msB[8];
#pragma unroll
        for (int i = 0; i < 8; ++i) {
            msA[i] = accA[i] * 0.25f;
            msB[i] = accB[i] * 0.25f;
        }
        STORE8(rowA + k0, msA);
        STORE8(rowB + k0, msB);
    }

    // r2 = relu(embWr1b[q] + msum @ Wr1[64:128])
    int qA = qtok[gidA], qB = qtok[gidB];
    LOAD8(embWr1b + qA * H + k0, accA);
    LOAD8(embWr1b + qB * H + k0, accB);
#pragma unroll 4
    for (int jq = 0; jq < 16; ++jq) {
        float4 a4 = *(const float4*)(rowA + jq * 4);
        float4 b4 = *(const float4*)(rowB + jq * 4);
        float aAv[4] = {a4.x, a4.y, a4.z, a4.w};
        float aBv[4] = {b4.x, b4.y, b4.z, b4.w};
#pragma unroll
        for (int jj = 0; jj < 4; ++jj) {
            const float4* w = (const float4*)(Wr1 + (H + jq * 4 + jj) * H + k0);
            float4 w0 = w[0], w1 = w[1];
            FMA8V(w0, w1, aAv[jj], accA);
            FMA8V(w0, w1, aBv[jj], accB);
        }
    }
    {
        float rA[8], rB[8];
#pragma unroll
        for (int i = 0; i < 8; ++i) {
            rA[i] = fmaxf(accA[i], 0.f);
            rB[i] = fmaxf(accB[i], 0.f);
        }
        STORE8(rowA + k0, rA);
        STORE8(rowB + k0, rB);
    }

    // logits = r2 @ Wr2 + br2
    LOAD8(br2 + k0, accA);
#pragma unroll
    for (int i = 0; i < 8; ++i) accB[i] = accA[i];
#pragma unroll 4
    for (int jq = 0; jq < 16; ++jq) {
        float4 a4 = *(const float4*)(rowA + jq * 4);
        float4 b4 = *(const float4*)(rowB + jq * 4);
        float aAv[4] = {a4.x, a4.y, a4.z, a4.w};
        float aBv[4] = {b4.x, b4.y, b4.z, b4.w};
#pragma unroll
        for (int jj = 0; jj < 4; ++jj) {
            const float4* w = (const float4*)(Wr2 + (jq * 4 + jj) * H + k0);
            float4 w0 = w[0], w1 = w[1];
            FMA8V(w0, w1, aAv[jj], accA);
            FMA8V(w0, w1, aBv[jj], accB);
        }
    }

    float4* oA = (float4*)(out + (size_t)gidA * H + k0);
    oA[0] = make_float4(accA[0], accA[1], accA[2], accA[3]);
    oA[1] = make_float4(accA[4], accA[5], accA[6], accA[7]);
    float4* oB = (float4*)(out + (size_t)gidB * H + k0);
    oB[0] = make_float4(accB[0], accB[1], accB[2], accB[3]);
    oB[1] = make_float4(accB[4], accB[5], accB[6], accB[7]);
}

extern "C" void kernel_launch(void* const* d_in, const int* in_sizes, int n_in,
                              void* d_out, int out_size, void* d_ws, size_t ws_size,
                              hipStream_t stream)
{
    const int*   seqs  = (const int*)d_in[0];
    const int*   qtok  = (const int*)d_in[1];
    const float* embed = (const float*)d_in[2];
    const float* W1    = (const float*)d_in[3];
    const float* b1    = (const float*)d_in[4];
    const float* W2    = (const float*)d_in[5];
    const float* b2    = (const float*)d_in[6];
    const float* Ww    = (const float*)d_in[7];
    const float* bw    = (const float*)d_in[8];
    const float* We    = (const float*)d_in[9];
    const float* be    = (const float*)d_in[10];
    const float* Wr1   = (const float*)d_in[11];
    const float* br1   = (const float*)d_in[12];
    const float* Wr2   = (const float*)d_in[13];
    const float* br2   = (const float*)d_in[14];
    float* out = (float*)d_out;
    float* ws  = (float*)d_ws;

    hipLaunchKernelGGL(k_setup_tables, dim3((NV * H + 255) / 256), dim3(256), 0, stream,
                       embed, W1, b1, Wr1, br1, ws);
    hipLaunchKernelGGL(k_setup_fuse, dim3((NSLOT * H * H + NSLOT * H + 255) / 256), dim3(256),
                       0, stream, W1, Ww, bw, ws);
    hipLaunchKernelGGL(k_main, dim3(NB / EPB), dim3(TPB), 0, stream,
                       W2, b2, Ww, bw, We, be, Wr1, Wr2, br2, qtok, seqs,
                       ws, ws + OFF_HL, out);
}

// Round 9
// 805.437 us; speedup vs baseline: 1.5582x; 1.0569x over previous
//
#include <hip/hip_runtime.h>

#define H       64
#define NSLOT   4
#define NSTEP   23          // SEQ_LEN - 1
#define NB      65536
#define NV      66          // VOCAB_SIZE + 2
#define SEQL    24
#define LPE     8           // lanes per element
#define TPB     512         // 8 waves
#define EPB     128         // elements per block (G=2 per lane)
#define ACTSTR  68          // act row stride: conflict-free b128 broadcast reads
#define MROW    68          // sM row stride
#define JL      48          // two-sided optimum: 48->40 = +106us (R4), 48->64 = +65us (R8)
#define MSSTR   (JL * MROW + 4)   // 3268 ; %32==4 (bank-offset invariant)

// R9 = R0 base (811us) + two loop-work cuts on the measured binding pipes:
//  (1) dead-last-step PV skipped (epilogue: h1/W2/evict/hlast only)  [R8-proven ~-25us]
//  (2) evict 8-lane reduce via DPP (VALU pipe) instead of __shfl_xor (ds_bpermute,
//      DS pipe): xor1=quad_perm[1,0,3,2], xor2=quad_perm[2,3,0,1], cross-quad=
//      row_half_mirror. Removes 24 DS instrs/step from the DS-bound loop.

// ---- workspace layout (float offsets) ----
#define OFF_EW1   0                  // embW1b  [NV][H] = embed@W1[:64] + b1
#define OFF_EWR1  (NV * H)           // embWr1b [NV][H] = embed@Wr1[:64] + br1
#define OFF_M     (2 * NV * H)       // M [4][64][64] = Ww @ W1slot_s
#define OFF_PB    (OFF_M + NSLOT * H * H)   // pb [4][64] = bw @ W1slot_s
#define OFF_HL    (OFF_PB + NSLOT * H)      // hlast [NB][4][64]  (64 MB)

__global__ __launch_bounds__(256) void k_setup_tables(
    const float* __restrict__ embed, const float* __restrict__ W1, const float* __restrict__ b1,
    const float* __restrict__ Wr1, const float* __restrict__ br1, float* __restrict__ ws)
{
    int idx = blockIdx.x * 256 + threadIdx.x;
    if (idx >= NV * H) return;
    int t = idx >> 6, k = idx & 63;
    float a1 = b1[k], a2 = br1[k];
    for (int j = 0; j < H; ++j) {
        float e = embed[t * H + j];
        a1 = fmaf(e, W1[j * H + k], a1);
        a2 = fmaf(e, Wr1[j * H + k], a2);
    }
    ws[OFF_EW1 + idx]  = a1;
    ws[OFF_EWR1 + idx] = a2;
}

__global__ __launch_bounds__(256) void k_setup_fuse(
    const float* __restrict__ W1, const float* __restrict__ Ww, const float* __restrict__ bw,
    float* __restrict__ ws)
{
    int idx = blockIdx.x * 256 + threadIdx.x;
    if (idx < NSLOT * H * H) {
        int s = idx >> 12, j = (idx >> 6) & 63, k = idx & 63;
        const float* w1s = W1 + (size_t)(H + s * H) * H;   // [p][k]
        float acc = 0.f;
        for (int p = 0; p < H; ++p)
            acc = fmaf(Ww[j * H + p], w1s[p * H + k], acc);
        ws[OFF_M + idx] = acc;
    } else if (idx < NSLOT * H * H + NSLOT * H) {
        int r = idx - NSLOT * H * H;
        int s = r >> 6, k = r & 63;
        const float* w1s = W1 + (size_t)(H + s * H) * H;
        float acc = 0.f;
        for (int p = 0; p < H; ++p)
            acc = fmaf(bw[p], w1s[p * H + k], acc);
        ws[OFF_PB + r] = acc;
    }
}

#define FMA8V(w0, w1, a, ACC) do {                                          \
    ACC[0]=fmaf((a),w0.x,ACC[0]); ACC[1]=fmaf((a),w0.y,ACC[1]);            \
    ACC[2]=fmaf((a),w0.z,ACC[2]); ACC[3]=fmaf((a),w0.w,ACC[3]);            \
    ACC[4]=fmaf((a),w1.x,ACC[4]); ACC[5]=fmaf((a),w1.y,ACC[5]);            \
    ACC[6]=fmaf((a),w1.z,ACC[6]); ACC[7]=fmaf((a),w1.w,ACC[7]);            \
} while (0)

#define LOAD8(ptr, A) do {                                                  \
    const float4* _b = (const float4*)(ptr);                                \
    float4 _b0 = _b[0], _b1 = _b[1];                                        \
    A[0]=_b0.x; A[1]=_b0.y; A[2]=_b0.z; A[3]=_b0.w;                        \
    A[4]=_b1.x; A[5]=_b1.y; A[6]=_b1.z; A[7]=_b1.w;                        \
} while (0)

#define STORE8(rowptr, A) do {                                              \
    float4* _d = (float4*)(rowptr);                                         \
    _d[0] = make_float4(A[0], A[1], A[2], A[3]);                            \
    _d[1] = make_float4(A[4], A[5], A[6], A[7]);                            \
} while (0)

// 8-lane group sum on the VALU pipe (DPP), not DS (ds_bpermute).
// Groups are 8-lane aligned -> quad_perm + row_half_mirror stay in-group.
__device__ __forceinline__ float grp8_sum(float x)
{
    x += __int_as_float(__builtin_amdgcn_update_dpp(
            0, __float_as_int(x), 0xB1 /*quad_perm[1,0,3,2] = xor1*/, 0xf, 0xf, false));
    x += __int_as_float(__builtin_amdgcn_update_dpp(
            0, __float_as_int(x), 0x4E /*quad_perm[2,3,0,1] = xor2*/, 0xf, 0xf, false));
    x += __int_as_float(__builtin_amdgcn_update_dpp(
            0, __float_as_int(x), 0x141 /*row_half_mirror = other quad*/, 0xf, 0xf, false));
    return x;
}

__global__ __launch_bounds__(TPB, 1) void k_main(
    const float* __restrict__ W2, const float* __restrict__ b2,
    const float* __restrict__ Ww, const float* __restrict__ bw,
    const float* __restrict__ We, const float* __restrict__ be,
    const float* __restrict__ Wr1, const float* __restrict__ Wr2, const float* __restrict__ br2,
    const int* __restrict__ qtok, const int* __restrict__ seqs,
    const float* __restrict__ ws, float* hl, float* __restrict__ out)
{
    __shared__ float sM[NSLOT * MSSTR];    // M rows j<JL  ~52 KB
    __shared__ float sAct[EPB * ACTSTR];   // [elem][j] rows, b128 broadcast reads ~35 KB
    __shared__ float sPb[NSLOT * 68];      // pb_s rows
    __shared__ float sWeS[8 * 36];         // per-chunk We slices [m][i*4+s]

    const int tid  = threadIdx.x;
    const int m    = tid & (LPE - 1);
    const int g    = tid >> 3;             // element group 0..63 (8 lanes, same wave)
    const int eA   = g;
    const int eB   = g + 64;
    const int gidA = blockIdx.x * EPB + eA;
    const int gidB = blockIdx.x * EPB + eB;
    const int k0   = m * 8;

    // ---- stage LDS ----
    if (tid < 256) {                        // sM: rows j<JL of each slot
        int s = tid >> 6, j = tid & 63;
        if (j < JL) {
            const float4* src = (const float4*)(ws + OFF_M + (size_t)(s * H + j) * H);
            float4* dst = (float4*)(sM + s * MSSTR + j * MROW);
#pragma unroll
            for (int k = 0; k < 16; ++k) dst[k] = src[k];
        }
    }
    if (tid >= 256 && tid < 512) {
        int r = tid - 256;                  // sPb: 4 x 64
        int s = r >> 6, k = r & 63;
        sPb[s * 68 + k] = ws[OFF_PB + s * H + k];
    }
    if (tid < 256) {
        int mm = tid >> 5, rem = tid & 31;  // sWeS[m][i*4+s] = We[(m*8+i)*4+s]
        sWeS[mm * 36 + rem] = We[tid];
    }
    __syncthreads();

    const float* embW1b  = ws + OFF_EW1;
    const float* embWr1b = ws + OFF_EWR1;
    const float* Mg      = ws + OFF_M;      // global M (rows j>=JL read from here)
    float* hlA = hl + (size_t)gidA * (NSLOT * H) + k0;
    float* hlB = hl + (size_t)gidB * (NSLOT * H) + k0;

    // register state per element: pmem 4x8 + contrib 8 + written-mask
    float pA0[8], pA1[8], pA2[8], pA3[8], cA[8];
    float pB0[8], pB1[8], pB2[8], pB3[8], cB[8];
#pragma unroll
    for (int i = 0; i < 8; ++i) {
        pA0[i]=0.f; pA1[i]=0.f; pA2[i]=0.f; pA3[i]=0.f; cA[i]=0.f;
        pB0[i]=0.f; pB1[i]=0.f; pB2[i]=0.f; pB3[i]=0.f; cB[i]=0.f;
    }
    int maskA = 0, maskB = 0;

    float b2r[8];
    LOAD8(b2 + k0, b2r);
    const float4 be4 = *(const float4*)be;

    int tokA = seqs[gidA * SEQL];
    int tokB = seqs[gidB * SEQL];

    float accA[8], accB[8];
    float* rowA = sAct + eA * ACTSTR;
    float* rowB = sAct + eB * ACTSTR;

#pragma unroll 1
    for (int t = 0; t < NSTEP - 1; ++t) {   // last step in epilogue (its PV is dead)
        int tokAn = seqs[gidA * SEQL + t + 1];
        int tokBn = seqs[gidB * SEQL + t + 1];

        // h1 = relu(embW1b[tok] + contrib) -> act rows
        {
            float hA[8], hB[8];
            LOAD8(embW1b + tokA * H + k0, hA);
            LOAD8(embW1b + tokB * H + k0, hB);
#pragma unroll
            for (int i = 0; i < 8; ++i) {
                hA[i] = fmaxf(hA[i] + cA[i], 0.f);
                hB[i] = fmaxf(hB[i] + cB[i], 0.f);
            }
            STORE8(rowA + k0, hA);
            STORE8(rowB + k0, hB);
        }

        // h2 = relu(h1 @ W2 + b2)   (W2 via VMEM; act b128 LDS broadcast)
#pragma unroll
        for (int i = 0; i < 8; ++i) { accA[i] = b2r[i]; accB[i] = b2r[i]; }
#pragma unroll 4
        for (int jq = 0; jq < 16; ++jq) {
            float4 a4 = *(const float4*)(rowA + jq * 4);
            float4 b4 = *(const float4*)(rowB + jq * 4);
            float aAv[4] = {a4.x, a4.y, a4.z, a4.w};
            float aBv[4] = {b4.x, b4.y, b4.z, b4.w};
#pragma unroll
            for (int jj = 0; jj < 4; ++jj) {
                const float4* w = (const float4*)(W2 + (jq * 4 + jj) * H + k0);
                float4 w0 = w[0], w1 = w[1];
                FMA8V(w0, w1, aAv[jj], accA);
                FMA8V(w0, w1, aBv[jj], accB);
            }
        }
        float h2A[8], h2B[8];
#pragma unroll
        for (int i = 0; i < 8; ++i) {
            h2A[i] = fmaxf(accA[i], 0.f);
            h2B[i] = fmaxf(accB[i], 0.f);
        }
        STORE8(rowA + k0, h2A);
        STORE8(rowB + k0, h2B);

        // evict logits in-register, then 8-lane DPP sum (VALU pipe, not DS)
        float lA0 = 0.f, lA1 = 0.f, lA2 = 0.f, lA3 = 0.f;
        float lB0 = 0.f, lB1 = 0.f, lB2 = 0.f, lB3 = 0.f;
        {
            const float* wsl = sWeS + m * 36;
#pragma unroll
            for (int i = 0; i < 8; ++i) {
                float4 we4 = *(const float4*)(wsl + i * 4);
                lA0 = fmaf(h2A[i], we4.x, lA0); lA1 = fmaf(h2A[i], we4.y, lA1);
                lA2 = fmaf(h2A[i], we4.z, lA2); lA3 = fmaf(h2A[i], we4.w, lA3);
                lB0 = fmaf(h2B[i], we4.x, lB0); lB1 = fmaf(h2B[i], we4.y, lB1);
                lB2 = fmaf(h2B[i], we4.z, lB2); lB3 = fmaf(h2B[i], we4.w, lB3);
            }
        }
        lA0 = grp8_sum(lA0) + be4.x; lA1 = grp8_sum(lA1) + be4.y;
        lA2 = grp8_sum(lA2) + be4.z; lA3 = grp8_sum(lA3) + be4.w;
        lB0 = grp8_sum(lB0) + be4.x; lB1 = grp8_sum(lB1) + be4.y;
        lB2 = grp8_sum(lB2) + be4.z; lB3 = grp8_sum(lB3) + be4.w;

        int eSA = 0; float bstA = lA0;               // first-max wins = jnp.argmax
        if (lA1 > bstA) { bstA = lA1; eSA = 1; }
        if (lA2 > bstA) { bstA = lA2; eSA = 2; }
        if (lA3 > bstA) { bstA = lA3; eSA = 3; }
        int eSB = 0; float bstB = lB0;
        if (lB1 > bstB) { bstB = lB1; eSB = 1; }
        if (lB2 > bstB) { bstB = lB2; eSB = 2; }
        if (lB3 > bstB) { bstB = lB3; eSB = 3; }

        bool a0 = (eSA == 0), a1 = (eSA == 1), a2 = (eSA == 2), a3 = (eSA == 3);
        bool b0 = (eSB == 0), b1 = (eSB == 1), b2_ = (eSB == 2), b3 = (eSB == 3);

        // hlast[e] <- h2  (global, fire-and-forget; read back only at tail)
        STORE8(hlA + eSA * H, h2A);
        STORE8(hlB + eSB * H, h2B);
        maskA |= (1 << eSA);
        maskB |= (1 << eSB);

        // pv = h2 @ M_e + pb_e   — rows j<JL from LDS, rows j>=JL from global.
        LOAD8(sPb + eSA * 68 + k0, accA);
        LOAD8(sPb + eSB * 68 + k0, accB);
        const float* lMA = sM + eSA * MSSTR + k0;
        const float* lMB = sM + eSB * MSSTR + k0;
#pragma unroll 4
        for (int jq = 0; jq < JL / 4; ++jq) {
            float4 a4 = *(const float4*)(rowA + jq * 4);
            float4 b4 = *(const float4*)(rowB + jq * 4);
            float dAv[4] = {a4.x, a4.y, a4.z, a4.w};
            float dBv[4] = {b4.x, b4.y, b4.z, b4.w};
#pragma unroll
            for (int jj = 0; jj < 4; ++jj) {
                int j = jq * 4 + jj;
                const float4* wa = (const float4*)(lMA + j * MROW);
                const float4* wb = (const float4*)(lMB + j * MROW);
                float4 wa0 = wa[0], wa1 = wa[1];
                float4 wb0 = wb[0], wb1 = wb[1];
                FMA8V(wa0, wa1, dAv[jj], accA);
                FMA8V(wb0, wb1, dBv[jj], accB);
            }
        }
        {
            const float* gMA = Mg + (size_t)(eSA * H + JL) * H + k0;  // rows JL..63
            const float* gMB = Mg + (size_t)(eSB * H + JL) * H + k0;
#pragma unroll 2
            for (int jq = JL / 4; jq < 16; ++jq) {
                float4 a4 = *(const float4*)(rowA + jq * 4);
                float4 b4 = *(const float4*)(rowB + jq * 4);
                float dAv[4] = {a4.x, a4.y, a4.z, a4.w};
                float dBv[4] = {b4.x, b4.y, b4.z, b4.w};
#pragma unroll
                for (int jj = 0; jj < 4; ++jj) {
                    int jr = (jq * 4 + jj) - JL;   // row offset within global part
                    const float4* wa = (const float4*)(gMA + jr * H);
                    const float4* wb = (const float4*)(gMB + jr * H);
                    float4 wa0 = wa[0], wa1 = wa[1];
                    float4 wb0 = wb[0], wb1 = wb[1];
                    FMA8V(wa0, wa1, dAv[jj], accA);
                    FMA8V(wb0, wb1, dBv[jj], accB);
                }
            }
        }

        // contrib += pv - pmem[e] ; pmem[e] = pv
#pragma unroll
        for (int i = 0; i < 8; ++i) {
            float pvA = accA[i], pvB = accB[i];
            float oldA = a0 ? pA0[i] : a1 ? pA1[i] : a2 ? pA2[i] : pA3[i];
            float oldB = b0 ? pB0[i] : b1 ? pB1[i] : b2_ ? pB2[i] : pB3[i];
            cA[i] += pvA - oldA;
            cB[i] += pvB - oldB;
            pA0[i] = a0 ? pvA : pA0[i];  pA1[i] = a1 ? pvA : pA1[i];
            pA2[i] = a2 ? pvA : pA2[i];  pA3[i] = a3 ? pvA : pA3[i];
            pB0[i] = b0 ? pvB : pB0[i];  pB1[i] = b1 ? pvB : pB1[i];
            pB2[i] = b2_ ? pvB : pB2[i]; pB3[i] = b3 ? pvB : pB3[i];
        }

        tokA = tokAn; tokB = tokBn;
    }

    // ---- epilogue step t = NSTEP-1: h1/W2/evict/hlast only (PV+contrib dead) ----
    {
        float hA[8], hB[8];
        LOAD8(embW1b + tokA * H + k0, hA);
        LOAD8(embW1b + tokB * H + k0, hB);
#pragma unroll
        for (int i = 0; i < 8; ++i) {
            hA[i] = fmaxf(hA[i] + cA[i], 0.f);
            hB[i] = fmaxf(hB[i] + cB[i], 0.f);
        }
        STORE8(rowA + k0, hA);
        STORE8(rowB + k0, hB);

#pragma unroll
        for (int i = 0; i < 8; ++i) { accA[i] = b2r[i]; accB[i] = b2r[i]; }
#pragma unroll 4
        for (int jq = 0; jq < 16; ++jq) {
            float4 a4 = *(const float4*)(rowA + jq * 4);
            float4 b4 = *(const float4*)(rowB + jq * 4);
            float aAv[4] = {a4.x, a4.y, a4.z, a4.w};
            float aBv[4] = {b4.x, b4.y, b4.z, b4.w};
#pragma unroll
            for (int jj = 0; jj < 4; ++jj) {
                const float4* w = (const float4*)(W2 + (jq * 4 + jj) * H + k0);
                float4 w0 = w[0], w1 = w[1];
                FMA8V(w0, w1, aAv[jj], accA);
                FMA8V(w0, w1, aBv[jj], accB);
            }
        }
        float h2A[8], h2B[8];
#pragma unroll
        for (int i = 0; i < 8; ++i) {
            h2A[i] = fmaxf(accA[i], 0.f);
            h2B[i] = fmaxf(accB[i], 0.f);
        }

        float lA0 = 0.f, lA1 = 0.f, lA2 = 0.f, lA3 = 0.f;
        float lB0 = 0.f, lB1 = 0.f, lB2 = 0.f, lB3 = 0.f;
        {
            const float* wsl = sWeS + m * 36;
#pragma unroll
            for (int i = 0; i < 8; ++i) {
                float4 we4 = *(const float4*)(wsl + i * 4);
                lA0 = fmaf(h2A[i], we4.x, lA0); lA1 = fmaf(h2A[i], we4.y, lA1);
                lA2 = fmaf(h2A[i], we4.z, lA2); lA3 = fmaf(h2A[i], we4.w, lA3);
                lB0 = fmaf(h2B[i], we4.x, lB0); lB1 = fmaf(h2B[i], we4.y, lB1);
                lB2 = fmaf(h2B[i], we4.z, lB2); lB3 = fmaf(h2B[i], we4.w, lB3);
            }
        }
        lA0 = grp8_sum(lA0) + be4.x; lA1 = grp8_sum(lA1) + be4.y;
        lA2 = grp8_sum(lA2) + be4.z; lA3 = grp8_sum(lA3) + be4.w;
        lB0 = grp8_sum(lB0) + be4.x; lB1 = grp8_sum(lB1) + be4.y;
        lB2 = grp8_sum(lB2) + be4.z; lB3 = grp8_sum(lB3) + be4.w;

        int eSA = 0; float bstA = lA0;
        if (lA1 > bstA) { bstA = lA1; eSA = 1; }
        if (lA2 > bstA) { bstA = lA2; eSA = 2; }
        if (lA3 > bstA) { bstA = lA3; eSA = 3; }
        int eSB = 0; float bstB = lB0;
        if (lB1 > bstB) { bstB = lB1; eSB = 1; }
        if (lB2 > bstB) { bstB = lB2; eSB = 2; }
        if (lB3 > bstB) { bstB = lB3; eSB = 3; }

        STORE8(hlA + eSA * H, h2A);
        STORE8(hlB + eSB * H, h2B);
        maskA |= (1 << eSA);
        maskB |= (1 << eSB);
    }

    // ---- tail: hsum = sum of surviving hlast slots (read back from global) ----
    __threadfence();   // drain hlast stores before read-back
    {
        float hsA[8] = {0,0,0,0,0,0,0,0}, hsB[8] = {0,0,0,0,0,0,0,0};
#pragma unroll
        for (int s = 0; s < NSLOT; ++s) {
            float vA[8], vB[8];
            LOAD8(hlA + s * H, vA);
            LOAD8(hlB + s * H, vB);
            float fA = ((maskA >> s) & 1) ? 1.f : 0.f;
            float fB = ((maskB >> s) & 1) ? 1.f : 0.f;
#pragma unroll
            for (int i = 0; i < 8; ++i) {
                hsA[i] = fmaf(fA, vA[i], hsA[i]);
                hsB[i] = fmaf(fB, vB[i], hsB[i]);
            }
        }
        STORE8(rowA + k0, hsA);
        STORE8(rowB + k0, hsB);
    }

    // msum = (hsum @ Ww + cnt*bw) / 4
    {
        float bwr[8];
        LOAD8(bw + k0, bwr);
        float cntA = (float)__popc(maskA), cntB = (float)__popc(maskB);
#pragma unroll
        for (int i = 0; i < 8; ++i) { accA[i] = cntA * bwr[i]; accB[i] = cntB * bwr[i]; }
    }
#pragma unroll 4
    for (int jq = 0; jq < 16; ++jq) {
        float4 a4 = *(const float4*)(rowA + jq * 4);
        float4 b4 = *(const float4*)(rowB + jq * 4);
        float aAv[4] = {a4.x, a4.y, a4.z, a4.w};
        float aBv[4] = {b4.x, b4.y, b4.z, b4.w};
#pragma unroll
        for (int jj = 0; jj < 4; ++jj) {
            const float4* w = (const float4*)(Ww + (jq * 4 + jj) * H + k0);
            float4 w0 = w[0], w1 = w[1];
            FMA8V(w0, w1, aAv[jj], accA);
            FMA8V(w0, w1, aBv[jj], accB);
        }
    }
    {
        float msA[8], msB[8];
#pragma unroll
        for (int i = 0; i < 8; ++i) {
            msA[i] = accA[i] * 0.25f;
            msB[i] = accB[i] * 0.25f;
        }
        STORE8(rowA + k0, msA);
        STORE8(rowB + k0, msB);
    }

    // r2 = relu(embWr1b[q] + msum @ Wr1[64:128])
    int qA = qtok[gidA], qB = qtok[gidB];
    LOAD8(embWr1b + qA * H + k0, accA);
    LOAD8(embWr1b + qB * H + k0, accB);
#pragma unroll 4
    for (int jq = 0; jq < 16; ++jq) {
        float4 a4 = *(const float4*)(rowA + jq * 4);
        float4 b4 = *(const float4*)(rowB + jq * 4);
        float aAv[4] = {a4.x, a4.y, a4.z, a4.w};
        float aBv[4] = {b4.x, b4.y, b4.z, b4.w};
#pragma unroll
        for (int jj = 0; jj < 4; ++jj) {
            const float4* w = (const float4*)(Wr1 + (H + jq * 4 + jj) * H + k0);
            float4 w0 = w[0], w1 = w[1];
            FMA8V(w0, w1, aAv[jj], accA);
            FMA8V(w0, w1, aBv[jj], accB);
        }
    }
    {
        float rA[8], rB[8];
#pragma unroll
        for (int i = 0; i < 8; ++i) {
            rA[i] = fmaxf(accA[i], 0.f);
            rB[i] = fmaxf(accB[i], 0.f);
        }
        STORE8(rowA + k0, rA);
        STORE8(rowB + k0, rB);
    }

    // logits = r2 @ Wr2 + br2
    LOAD8(br2 + k0, accA);
#pragma unroll
    for (int i = 0; i < 8; ++i) accB[i] = accA[i];
#pragma unroll 4
    for (int jq = 0; jq < 16; ++jq) {
        float4 a4 = *(const float4*)(rowA + jq * 4);
        float4 b4 = *(const float4*)(rowB + jq * 4);
        float aAv[4] = {a4.x, a4.y, a4.z, a4.w};
        float aBv[4] = {b4.x, b4.y, b4.z, b4.w};
#pragma unroll
        for (int jj = 0; jj < 4; ++jj) {
            const float4* w = (const float4*)(Wr2 + (jq * 4 + jj) * H + k0);
            float4 w0 = w[0], w1 = w[1];
            FMA8V(w0, w1, aAv[jj], accA);
            FMA8V(w0, w1, aBv[jj], accB);
        }
    }

    float4* oA = (float4*)(out + (size_t)gidA * H + k0);
    oA[0] = make_float4(accA[0], accA[1], accA[2], accA[3]);
    oA[1] = make_float4(accA[4], accA[5], accA[6], accA[7]);
    float4* oB = (float4*)(out + (size_t)gidB * H + k0);
    oB[0] = make_float4(accB[0], accB[1], accB[2], accB[3]);
    oB[1] = make_float4(accB[4], accB[5], accB[6], accB[7]);
}

extern "C" void kernel_launch(void* const* d_in, const int* in_sizes, int n_in,
                              void* d_out, int out_size, void* d_ws, size_t ws_size,
                              hipStream_t stream)
{
    const int*   seqs  = (const int*)d_in[0];
    const int*   qtok  = (const int*)d_in[1];
    const float* embed = (const float*)d_in[2];
    const float* W1    = (const float*)d_in[3];
    const float* b1    = (const float*)d_in[4];
    const float* W2    = (const float*)d_in[5];
    const float* b2    = (const float*)d_in[6];
    const float* Ww    = (const float*)d_in[7];
    const float* bw    = (const float*)d_in[8];
    const float* We    = (const float*)d_in[9];
    const float* be    = (const float*)d_in[10];
    const float* Wr1   = (const float*)d_in[11];
    const float* br1   = (const float*)d_in[12];
    const float* Wr2   = (const float*)d_in[13];
    const float* br2   = (const float*)d_in[14];
    float* out = (float*)d_out;
    float* ws  = (float*)d_ws;

    hipLaunchKernelGGL(k_setup_tables, dim3((NV * H + 255) / 256), dim3(256), 0, stream,
                       embed, W1, b1, Wr1, br1, ws);
    hipLaunchKernelGGL(k_setup_fuse, dim3((NSLOT * H * H + NSLOT * H + 255) / 256), dim3(256),
                       0, stream, W1, Ww, bw, ws);
    hipLaunchKernelGGL(k_main, dim3(NB / EPB), dim3(TPB), 0, stream,
                       W2, b2, Ww, bw, We, be, Wr1, Wr2, br2, qtok, seqs,
                       ws, ws + OFF_HL, out);
}